// Round 6
// baseline (275.712 us; speedup 1.0000x reference)
//
#include <hip/hip_runtime.h>
#include <stdint.h>

#define Bn 64
#define Sn 512
#define SPn 520
#define Dn 768
#define Fn 256
#define JSTRIDE 393216   // 256 rows * 1536 B : tap stride within Wp
#define ABUF 16640       // 260 rows * 64 B
#define BSLOT 8192       // 128 rows * 64 B

typedef short bf16x8 __attribute__((ext_vector_type(8)));
typedef float f32x4 __attribute__((ext_vector_type(4)));

static __device__ __forceinline__ unsigned short f2bf(float f) {
  union { float f; unsigned u; } v; v.f = f;
  unsigned r = v.u + 0x7FFFu + ((v.u >> 16) & 1u);
  return (unsigned short)(r >> 16);
}

// async global->LDS, 16B/lane; LDS dest = wave-uniform base + lane*16
static __device__ __forceinline__ void gload16(const void* g, void* l) {
  __builtin_amdgcn_global_load_lds(
      (const __attribute__((address_space(1))) unsigned int*)g,
      (__attribute__((address_space(3))) unsigned int*)l, 16, 0, 0);
}

template<int N> __device__ __forceinline__ void waitv() {
  static_assert(N == 0 || N == 2 || N == 7, "");
  if constexpr (N == 0) asm volatile("s_waitcnt vmcnt(0)" ::: "memory");
  else if constexpr (N == 2) asm volatile("s_waitcnt vmcnt(2)" ::: "memory");
  else asm volatile("s_waitcnt vmcnt(7)" ::: "memory");
}

template<int S, typename T, int N>
static __device__ __forceinline__ T (&sel(T (&a)[N], T (&b)[N]))[N] {
  if constexpr (S) return b; else return a;
}

// ---------------------------------------------------------------------------
// 1) stable compaction + f32->bf16: hc[b][t][d]; rows t>=L left stale
// ---------------------------------------------------------------------------
__global__ __launch_bounds__(256) void compact_kernel(
    const int* __restrict__ x, const float* __restrict__ h,
    unsigned short* __restrict__ hc, int* __restrict__ Lout) {
  int b = blockIdx.x, rblk = blockIdx.y;
  __shared__ unsigned long long masks[8];
  __shared__ short sidx[Sn];
  int tid = threadIdx.x, lane = tid & 63, wv = tid >> 6;
  for (int c = wv; c < 8; c += 4) {
    bool pred = x[b * Sn + c * 64 + lane] != 0;
    unsigned long long m = __ballot(pred);
    if (lane == 0) masks[c] = m;
  }
  __syncthreads();
  int pref[9]; pref[0] = 0;
  #pragma unroll
  for (int c = 0; c < 8; ++c) pref[c + 1] = pref[c] + __popcll(masks[c]);
  int L = pref[8];
  for (int p = tid; p < Sn; p += 256) {
    int c = p >> 6, l = p & 63;
    unsigned long long m = masks[c];
    if ((m >> l) & 1ull)
      sidx[pref[c] + __popcll(m & ((1ull << l) - 1ull))] = (short)p;
  }
  if (rblk == 0 && tid == 0) Lout[b] = L;
  __syncthreads();
  int r0 = rblk * 65;  // 8 * 65 = 520 rows
  for (int r = r0 + wv; r < r0 + 65; r += 4) {
    if (r < L) {
      unsigned short* dst = hc + ((size_t)b * SPn + r) * Dn;
      const float* src = h + ((size_t)b * Sn + sidx[r]) * Dn;
      #pragma unroll
      for (int c = 0; c < 3; ++c) {
        int d = c * 256 + lane * 4;
        float4 v = *(const float4*)(src + d);
        ushort4 o = { f2bf(v.x), f2bf(v.y), f2bf(v.z), f2bf(v.w) };
        *(ushort4*)(dst + d) = o;
      }
    }
  }
}

// ---------------------------------------------------------------------------
// 1.5) plan: 16-aligned per-batch segments packed densely; rowmap[p]=(b,L,t)
// ---------------------------------------------------------------------------
__global__ __launch_bounds__(256) void plan_kernel(
    const int* __restrict__ Lbuf, int* __restrict__ plan, int* __restrict__ rowmap) {
  __shared__ int sOff[65];
  __shared__ int sL[64];
  int tid = threadIdx.x;
  if (tid < 64) {
    int L = Lbuf[tid];
    int SL = (L + 15) & ~15;
    int pre = SL;
    #pragma unroll
    for (int off = 1; off < 64; off <<= 1) {
      int y = __shfl_up(pre, off);
      if (tid >= off) pre += y;
    }
    sOff[tid] = pre - SL;           // exclusive prefix
    sL[tid] = L;
    if (tid == 63) { sOff[64] = pre; plan[0] = (pre + 255) >> 8; }
  }
  __syncthreads();
  int M = sOff[64];
  for (int b = 0; b < 64; ++b) {
    int off = sOff[b], L = sL[b];
    int SL = (L + 15) & ~15;
    int enc = (b << 20) | (L << 10);
    for (int t = tid; t < SL; t += 256) rowmap[off + t] = enc | t;
  }
  for (int p = M + tid; p < M + 264; p += 256)
    rowmap[p] = 512;                // sentinel: b=0, L=0, t=512
}

// ---------------------------------------------------------------------------
// 2) weight repack via LDS bounce: coalesced reads AND writes
// ---------------------------------------------------------------------------
__global__ __launch_bounds__(256) void wpack_kernel(
    const float* __restrict__ w2, const float* __restrict__ w3,
    const float* __restrict__ w4, const float* __restrict__ w5,
    unsigned short* __restrict__ Wp) {
  __shared__ float sf[3840];        // up to 768*5
  int bb = blockIdx.x;
  int br = bb >> 8, f = bb & 255, k = br + 2;
  const float* w = (br == 0) ? w2 : (br == 1) ? w3 : (br == 2) ? w4 : w5;
  int mBase = 256 * ((br * (br + 3)) >> 1);
  const float* src = w + (size_t)f * Dn * k;
  int n = Dn * k;
  for (int e = threadIdx.x; e < n; e += 256) sf[e] = src[e];
  __syncthreads();
  for (int j = 0; j < k; ++j) {
    unsigned short* dst = Wp + (size_t)(mBase + j * 256 + f) * Dn;
    for (int d = threadIdx.x; d < Dn; d += 256) dst[d] = f2bf(sf[d * k + j]);
  }
}

// ---------------------------------------------------------------------------
// 3) packed-M conv-GEMM, register-pipelined fragments + ring-4 B slots.
//    Step s: issue gloads for slot s+3; ds_read (pre-read) fragments for step
//    s+1 from slot s+1 / A dbuf; MFMA on regs loaded at s-1; counted waitv;
//    one raw s_barrier. vmcnt never drains to 0 in the main loop.
// ---------------------------------------------------------------------------
static __device__ __forceinline__ void issueA(
    int d0i, char* sA, const char* const (&gA)[4], const char* gAt,
    int lane, int wvoff) {
  int aoff = (d0i + 1) * 64;
  char* nA = sA + ((d0i + 1) & 1) * ABUF;
  #pragma unroll
  for (int p = 0; p < 4; ++p) gload16(gA[p] + aoff, nA + p * 4096 + wvoff);
  if (lane < 16) gload16(gAt + aoff, nA + 16384);   // rows 256..259
}

template<int JN>
static __device__ __forceinline__ void preread(
    const char* pA, const char* pB, int wv, int lrow, int lg,
    bf16x8 (&Af)[4], bf16x8 (&Bf)[8]) {
  #pragma unroll
  for (int n = 0; n < 8; ++n) {
    int row = n * 16 + lrow;
    Bf[n] = *(const bf16x8*)(pB + row * 64 + ((lg ^ ((row >> 1) & 3)) << 4));
  }
  #pragma unroll
  for (int m = 0; m < 4; ++m) {
    int row = wv * 64 + m * 16 + lrow + JN;
    Af[m] = *(const bf16x8*)(pA + row * 64 + ((lg ^ ((row >> 1) & 3)) << 4));
  }
}

static __device__ __forceinline__ void domfma(
    bf16x8 (&Af)[4], bf16x8 (&Bf)[8], f32x4 (&acc)[4][8]) {
  __builtin_amdgcn_s_setprio(1);
  #pragma unroll
  for (int n = 0; n < 8; ++n)
    #pragma unroll
    for (int m = 0; m < 4; ++m)
      acc[m][n] = __builtin_amdgcn_mfma_f32_16x16x32_bf16(Af[m], Bf[n], acc[m][n], 0, 0, 0);
  __builtin_amdgcn_s_setprio(0);
}

template<int J, int W, int J3, int DADD3, int DOA, int SET, int JN, int DN, int AFIRST>
static __device__ __forceinline__ void step(
    int d0i, int bsl0, char* sA, char* sB,
    const char* const (&gA)[4], const char* gAt, const char* gB0, const char* gB1,
    int lane, int wv, int lrow, int lg, int wvoff,
    bf16x8 (&Af0)[4], bf16x8 (&Bf0)[8], bf16x8 (&Af1)[4], bf16x8 (&Bf1)[8],
    f32x4 (&acc)[4][8]) {
  if constexpr (AFIRST) { if (d0i < 23) issueA(d0i, sA, gA, gAt, lane, wvoff); }
  {
    int dsl = (bsl0 + J + 3) & 3;
    int boff = J3 * JSTRIDE + (d0i + DADD3) * 64;
    char* bdst = sB + dsl * BSLOT + wvoff;
    gload16(gB0 + boff, bdst);
    gload16(gB1 + boff, bdst + 4096);
  }
  if constexpr (DOA && !AFIRST) { if (d0i < 23) issueA(d0i, sA, gA, gAt, lane, wvoff); }
  {
    int psl = (bsl0 + J + 1) & 3;
    preread<JN>(sA + ((d0i + DN) & 1) * ABUF, sB + psl * BSLOT, wv, lrow, lg,
                sel<SET ^ 1>(Af0, Af1), sel<SET ^ 1>(Bf0, Bf1));
  }
  domfma(sel<SET>(Af0, Af1), sel<SET>(Bf0, Bf1), acc);
  __builtin_amdgcn_sched_barrier(0);
  waitv<W>();
  __builtin_amdgcn_sched_barrier(0);
  __builtin_amdgcn_s_barrier();
  __builtin_amdgcn_sched_barrier(0);
}

#define SA bsl0, sA, sB, gA, gAt, gB0, gB1, lane, wv, lrow, lg, wvoff, Af0, Bf0, Af1, Bf1, acc

template<int KK>
static __device__ __forceinline__ void conv_loop(
    char* sA, char* sB, const char* const (&gA)[4], const char* gAt,
    const char* gB0, const char* gB1,
    int lane, int wv, int lrow, int lg, int wvoff, f32x4 (&acc)[4][8]) {
  bf16x8 Af0[4], Bf0[8], Af1[4], Bf1[8];
  // prologue: B slots 0,1,2 (= steps 0,1,2) + A(0); drain; pre-read set0.
  gload16(gB0, sB + wvoff);
  gload16(gB1, sB + 4096 + wvoff);
  gload16(gB0 + JSTRIDE, sB + BSLOT + wvoff);
  gload16(gB1 + JSTRIDE, sB + BSLOT + 4096 + wvoff);
  constexpr int OFF2 = (KK >= 3) ? 2 * JSTRIDE : 64;   // step2 = (0,2) or (1,0)
  gload16(gB0 + OFF2, sB + 2 * BSLOT + wvoff);
  gload16(gB1 + OFF2, sB + 2 * BSLOT + 4096 + wvoff);
  #pragma unroll
  for (int p = 0; p < 4; ++p) gload16(gA[p], sA + p * 4096 + wvoff);
  if (lane < 16) gload16(gAt, sA + 16384);
  waitv<0>();
  __builtin_amdgcn_s_barrier();
  preread<0>(sA, sB, wv, lrow, lg, Af0, Bf0);

  int bsl0 = 0;
  if constexpr (KK == 5) {
    for (int dd = 0; dd < 22; dd += 2) {
      step<0,7,3,0,1, 0,1,0,0>(dd, SA);
      step<1,7,4,0,0, 1,2,0,0>(dd, SA);
      step<2,2,0,1,0, 0,3,0,0>(dd, SA);
      step<3,2,1,1,0, 1,4,0,0>(dd, SA);
      step<4,2,2,1,0, 0,0,1,0>(dd, SA);
      bsl0 = (bsl0 + 1) & 3;
      step<0,7,3,0,1, 1,1,0,0>(dd + 1, SA);
      step<1,7,4,0,0, 0,2,0,0>(dd + 1, SA);
      step<2,2,0,1,0, 1,3,0,0>(dd + 1, SA);
      step<3,2,1,1,0, 0,4,0,0>(dd + 1, SA);
      step<4,2,2,1,0, 1,0,1,0>(dd + 1, SA);
      bsl0 = (bsl0 + 1) & 3;
    }
    step<0,7,3,0,1, 0,1,0,0>(22, SA);
    step<1,7,4,0,0, 1,2,0,0>(22, SA);
    step<2,2,0,1,0, 0,3,0,0>(22, SA);
    step<3,2,1,1,0, 1,4,0,0>(22, SA);
    step<4,2,2,1,0, 0,0,1,0>(22, SA);
    bsl0 = (bsl0 + 1) & 3;
    step<0,2,3,0,0, 1,1,0,0>(23, SA);   // tail d0: W=2 (no A in queue), no A issue
    step<1,2,4,0,0, 0,2,0,0>(23, SA);
    step<2,2,0,1,0, 1,3,0,0>(23, SA);
    step<3,2,1,1,0, 0,4,0,0>(23, SA);
    step<4,2,2,1,0, 1,0,1,0>(23, SA);
  } else if constexpr (KK == 4) {
    for (int dd = 0; dd < 23; ++dd) {
      step<0,7,3,0,1, 0,1,0,0>(dd, SA);
      step<1,7,0,1,0, 1,2,0,0>(dd, SA);
      step<2,2,1,1,0, 0,3,0,0>(dd, SA);
      step<3,2,2,1,0, 1,0,1,0>(dd, SA);
    }
    step<0,2,3,0,0, 0,1,0,0>(23, SA);
    step<1,2,0,1,0, 1,2,0,0>(23, SA);
    step<2,2,1,1,0, 0,3,0,0>(23, SA);
    step<3,2,2,1,0, 1,0,1,0>(23, SA);
  } else if constexpr (KK == 3) {
    for (int dd = 0; dd < 22; dd += 2) {
      step<0,7,0,1,1, 0,1,0,0>(dd, SA);
      step<1,2,1,1,0, 1,2,0,0>(dd, SA);
      step<2,2,2,1,0, 0,0,1,0>(dd, SA);
      bsl0 = (bsl0 + 3) & 3;
      step<0,7,0,1,1, 1,1,0,0>(dd + 1, SA);
      step<1,2,1,1,0, 0,2,0,0>(dd + 1, SA);
      step<2,2,2,1,0, 1,0,1,0>(dd + 1, SA);
      bsl0 = (bsl0 + 3) & 3;
    }
    step<0,7,0,1,1, 0,1,0,0>(22, SA);
    step<1,2,1,1,0, 1,2,0,0>(22, SA);
    step<2,2,2,1,0, 0,0,1,0>(22, SA);
    bsl0 = (bsl0 + 3) & 3;
    step<0,2,0,1,0, 1,1,0,0>(23, SA);
    step<1,2,1,1,0, 0,2,0,0>(23, SA);
    step<2,2,2,1,0, 1,0,1,0>(23, SA);
  } else {  // KK == 2, A-first at j=0 (A needed same-d0)
    for (int dd = 0; dd < 23; ++dd) {
      step<0,2,1,1,1, 0,1,0,1>(dd, SA);
      step<1,2,0,2,0, 1,0,1,0>(dd, SA);
      bsl0 = (bsl0 + 2) & 3;
    }
    step<0,2,1,1,0, 0,1,0,0>(23, SA);
    step<1,2,0,2,0, 1,0,1,0>(23, SA);
  }
  waitv<0>();                       // no DMA may outlive this block's LDS
}

__global__ __launch_bounds__(256, 2) void conv_kernel(
    const unsigned short* __restrict__ hc, const unsigned short* __restrict__ Wp,
    const float* __restrict__ b2, const float* __restrict__ b3,
    const float* __restrict__ b4, const float* __restrict__ b5,
    const int* __restrict__ plan, const int* __restrict__ rowmap,
    int* __restrict__ feats) {
  __shared__ char smem[2 * ABUF + 4 * BSLOT];   // 66048 B -> 2 blocks/CU
  char* sA = smem;
  char* sB = smem + 2 * ABUF;
  int idx = blockIdx.x;
  // XCD-aware decode: tile ≡ xcd (mod 8) so all 8 subs of a tile share an XCD
  int xcd = idx & 7, s2 = idx >> 3;
  int sub = s2 & 7, tile = xcd + ((s2 >> 3) << 3);
  if (tile >= plan[0]) return;
  int br = 3 - (sub >> 1), ff = sub & 1, kk = br + 2;
  int mBase = 256 * ((br * (br + 3)) >> 1) + ff * 128;
  const float* bias = (br == 0) ? b2 : (br == 1) ? b3 : (br == 2) ? b4 : b5;
  int tid = threadIdx.x, lane = tid & 63, wv = tid >> 6;
  int lrow = lane & 15, lg = lane >> 4;
  int wvoff = wv * 1024;
  int P0 = tile << 8;

  // per-lane pre-swizzled global sources (d0-invariant)
  const char* gA[4];
  #pragma unroll
  for (int p = 0; p < 4; ++p) {
    int c = p * 256 + tid;
    int row = c >> 2, sgp = c & 3;
    int rm = rowmap[P0 + row];
    int bb_ = rm >> 20, t = rm & 1023;
    int seg = sgp ^ ((row >> 1) & 3);
    gA[p] = (const char*)(hc + ((size_t)(bb_ * SPn + t)) * Dn + seg * 8);
  }
  const char* gAt;
  {
    int l = lane & 15;               // rows 256..259 (only lanes<16 used)
    int row = 256 + (l >> 2), sgp = l & 3;
    int rm = rowmap[P0 + row];
    int bb_ = rm >> 20, t = rm & 1023;
    int seg = sgp ^ ((row >> 1) & 3);
    gAt = (const char*)(hc + ((size_t)(bb_ * SPn + t)) * Dn + seg * 8);
  }
  const char* gB0;
  const char* gB1;
  {
    int row = tid >> 2, sgp = tid & 3;
    int seg = sgp ^ ((row >> 1) & 3);
    gB0 = (const char*)(Wp + ((size_t)(mBase + row)) * Dn + seg * 8);
    int c = 256 + tid;
    row = c >> 2; sgp = c & 3;
    seg = sgp ^ ((row >> 1) & 3);
    gB1 = (const char*)(Wp + ((size_t)(mBase + row)) * Dn + seg * 8);
  }

  f32x4 acc[4][8];
  #pragma unroll
  for (int m = 0; m < 4; ++m)
    #pragma unroll
    for (int n = 0; n < 8; ++n) acc[m][n] = (f32x4)0.f;

  switch (br) {
    case 3: conv_loop<5>(sA, sB, gA, gAt, gB0, gB1, lane, wv, lrow, lg, wvoff, acc); break;
    case 2: conv_loop<4>(sA, sB, gA, gAt, gB0, gB1, lane, wv, lrow, lg, wvoff, acc); break;
    case 1: conv_loop<3>(sA, sB, gA, gAt, gB0, gB1, lane, wv, lrow, lg, wvoff, acc); break;
    default: conv_loop<2>(sA, sB, gA, gAt, gB0, gB1, lane, wv, lrow, lg, wvoff, acc); break;
  }

  // epilogue: per m-fragment single batch; bias + mask + relu + pool + atomic
  int rmv[4];
  #pragma unroll
  for (int m = 0; m < 4; ++m) rmv[m] = rowmap[P0 + wv * 64 + m * 16];
  #pragma unroll
  for (int n = 0; n < 8; ++n) {
    int fg = ff * 128 + n * 16 + lrow;
    float bv = bias[fg];
    #pragma unroll
    for (int m = 0; m < 4; ++m) {
      int bb_ = rmv[m] >> 20;
      int Lb = (rmv[m] >> 10) & 1023;
      int t0 = (rmv[m] & 1023) + lg * 4;
      int vlim = Lb - kk + 1;
      float pmax = 0.f;
      #pragma unroll
      for (int i = 0; i < 4; ++i) {
        float v = acc[m][n][i] + bv;
        pmax = fmaxf(pmax, (t0 + i < vlim) ? fmaxf(v, 0.f) : 0.f);
      }
      pmax = fmaxf(pmax, __shfl_xor(pmax, 16));
      pmax = fmaxf(pmax, __shfl_xor(pmax, 32));
      if (lane < 16 && pmax > 0.f)
        atomicMax(feats + bb_ * 1024 + br * 256 + fg, __float_as_int(pmax));
    }
  }
}

// ---------------------------------------------------------------------------
// 4) FC + sigmoid
// ---------------------------------------------------------------------------
__global__ __launch_bounds__(64) void fc_kernel(
    const int* __restrict__ feats, const float* __restrict__ fcw,
    const float* __restrict__ fcb, float* __restrict__ out) {
  int b = blockIdx.x, lane = threadIdx.x;
  float acc = 0.f;
  for (int i = lane; i < 1024; i += 64)
    acc += __int_as_float(feats[b * 1024 + i]) * fcw[i];
  #pragma unroll
  for (int off = 32; off; off >>= 1) acc += __shfl_xor(acc, off);
  if (lane == 0) out[b] = 1.f / (1.f + expf(-(acc + fcb[0])));
}

extern "C" void kernel_launch(void* const* d_in, const int* in_sizes, int n_in,
                              void* d_out, int out_size, void* d_ws, size_t ws_size,
                              hipStream_t stream) {
  const int*   x   = (const int*)d_in[0];
  const float* h   = (const float*)d_in[1];
  const float* w2  = (const float*)d_in[2];
  const float* b2  = (const float*)d_in[3];
  const float* w3  = (const float*)d_in[4];
  const float* b3  = (const float*)d_in[5];
  const float* w4  = (const float*)d_in[6];
  const float* b4  = (const float*)d_in[7];
  const float* w5  = (const float*)d_in[8];
  const float* b5  = (const float*)d_in[9];
  const float* fcw = (const float*)d_in[10];
  const float* fcb = (const float*)d_in[11];
  float* out = (float*)d_out;
  char* ws = (char*)d_ws;
  unsigned short* hc = (unsigned short*)ws;               // 64*520*768*2 = 51,118,080
  unsigned short* Wp = (unsigned short*)(ws + 51118080);  // 3584*768*2   =  5,505,024
  int* feats  = (int*)(ws + 56623104);                    // 64*1024*4    =    262,144
  int* Lbuf   = (int*)(ws + 56885248);                    // 64*4
  int* plan   = (int*)(ws + 56885504);                    // 4 ints
  int* rowmap = (int*)(ws + 56885520);                    // (32768+264)*4

  hipMemsetAsync(feats, 0, 64 * 1024 * 4, stream);        // zero bits == 0.0f == relu floor
  compact_kernel<<<dim3(64, 8), 256, 0, stream>>>(x, h, hc, Lbuf);
  plan_kernel<<<1, 256, 0, stream>>>(Lbuf, plan, rowmap);
  wpack_kernel<<<1024, 256, 0, stream>>>(w2, w3, w4, w5, Wp);
  conv_kernel<<<1024, 256, 0, stream>>>(hc, Wp, b2, b3, b4, b5, plan, rowmap, feats);
  fc_kernel<<<64, 64, 0, stream>>>(feats, fcw, fcb, out);
}

// Round 7
// 253.942 us; speedup vs baseline: 1.0857x; 1.0857x over previous
//
#include <hip/hip_runtime.h>
#include <stdint.h>

#define Bn 64
#define Sn 512
#define SPn 520
#define Dn 768
#define Fn 256
#define JSTRIDE 393216   // 256 rows * 1536 B : tap stride within Wp
#define ABUF 16640       // 260 rows * 64 B
#define BSLOT 8192       // 128 rows * 64 B

typedef short bf16x8 __attribute__((ext_vector_type(8)));
typedef float f32x4 __attribute__((ext_vector_type(4)));

static __device__ __forceinline__ unsigned short f2bf(float f) {
  union { float f; unsigned u; } v; v.f = f;
  unsigned r = v.u + 0x7FFFu + ((v.u >> 16) & 1u);
  return (unsigned short)(r >> 16);
}

// async global->LDS, 16B/lane; LDS dest = wave-uniform base + lane*16
static __device__ __forceinline__ void gload16(const void* g, void* l) {
  __builtin_amdgcn_global_load_lds(
      (const __attribute__((address_space(1))) unsigned int*)g,
      (__attribute__((address_space(3))) unsigned int*)l, 16, 0, 0);
}

template<int N> __device__ __forceinline__ void waitv() {
  static_assert(N == 0 || N == 2 || N == 7, "");
  if constexpr (N == 0) asm volatile("s_waitcnt vmcnt(0)" ::: "memory");
  else if constexpr (N == 2) asm volatile("s_waitcnt vmcnt(2)" ::: "memory");
  else asm volatile("s_waitcnt vmcnt(7)" ::: "memory");
}

template<int S, typename T, int N>
static __device__ __forceinline__ T (&sel(T (&a)[N], T (&b)[N]))[N] {
  if constexpr (S) return b; else return a;
}

// ---------------------------------------------------------------------------
// 1) stable compaction + f32->bf16: hc[b][t][d]; rows t>=L left stale
// ---------------------------------------------------------------------------
__global__ __launch_bounds__(256) void compact_kernel(
    const int* __restrict__ x, const float* __restrict__ h,
    unsigned short* __restrict__ hc, int* __restrict__ Lout) {
  int b = blockIdx.x, rblk = blockIdx.y;
  __shared__ unsigned long long masks[8];
  __shared__ short sidx[Sn];
  int tid = threadIdx.x, lane = tid & 63, wv = tid >> 6;
  for (int c = wv; c < 8; c += 4) {
    bool pred = x[b * Sn + c * 64 + lane] != 0;
    unsigned long long m = __ballot(pred);
    if (lane == 0) masks[c] = m;
  }
  __syncthreads();
  int pref[9]; pref[0] = 0;
  #pragma unroll
  for (int c = 0; c < 8; ++c) pref[c + 1] = pref[c] + __popcll(masks[c]);
  int L = pref[8];
  for (int p = tid; p < Sn; p += 256) {
    int c = p >> 6, l = p & 63;
    unsigned long long m = masks[c];
    if ((m >> l) & 1ull)
      sidx[pref[c] + __popcll(m & ((1ull << l) - 1ull))] = (short)p;
  }
  if (rblk == 0 && tid == 0) Lout[b] = L;
  __syncthreads();
  int r0 = rblk * 65;  // 8 * 65 = 520 rows
  for (int r = r0 + wv; r < r0 + 65; r += 4) {
    if (r < L) {
      unsigned short* dst = hc + ((size_t)b * SPn + r) * Dn;
      const float* src = h + ((size_t)b * Sn + sidx[r]) * Dn;
      #pragma unroll
      for (int c = 0; c < 3; ++c) {
        int d = c * 256 + lane * 4;
        float4 v = *(const float4*)(src + d);
        ushort4 o = { f2bf(v.x), f2bf(v.y), f2bf(v.z), f2bf(v.w) };
        *(ushort4*)(dst + d) = o;
      }
    }
  }
}

// ---------------------------------------------------------------------------
// 1.5) plan: 16-aligned per-batch segments packed densely; rowmap[p]=(b,L,t)
// ---------------------------------------------------------------------------
__global__ __launch_bounds__(256) void plan_kernel(
    const int* __restrict__ Lbuf, int* __restrict__ plan, int* __restrict__ rowmap) {
  __shared__ int sOff[65];
  __shared__ int sL[64];
  int tid = threadIdx.x;
  if (tid < 64) {
    int L = Lbuf[tid];
    int SL = (L + 15) & ~15;
    int pre = SL;
    #pragma unroll
    for (int off = 1; off < 64; off <<= 1) {
      int y = __shfl_up(pre, off);
      if (tid >= off) pre += y;
    }
    sOff[tid] = pre - SL;           // exclusive prefix
    sL[tid] = L;
    if (tid == 63) { sOff[64] = pre; plan[0] = (pre + 255) >> 8; }
  }
  __syncthreads();
  int M = sOff[64];
  for (int b = 0; b < 64; ++b) {
    int off = sOff[b], L = sL[b];
    int SL = (L + 15) & ~15;
    int enc = (b << 20) | (L << 10);
    for (int t = tid; t < SL; t += 256) rowmap[off + t] = enc | t;
  }
  for (int p = M + tid; p < M + 264; p += 256)
    rowmap[p] = 512;                // sentinel: b=0, L=0, t=512
}

// ---------------------------------------------------------------------------
// 2) weight repack via LDS bounce: coalesced reads AND writes
// ---------------------------------------------------------------------------
__global__ __launch_bounds__(256) void wpack_kernel(
    const float* __restrict__ w2, const float* __restrict__ w3,
    const float* __restrict__ w4, const float* __restrict__ w5,
    unsigned short* __restrict__ Wp) {
  __shared__ float sf[3840];        // up to 768*5
  int bb = blockIdx.x;
  int br = bb >> 8, f = bb & 255, k = br + 2;
  const float* w = (br == 0) ? w2 : (br == 1) ? w3 : (br == 2) ? w4 : w5;
  int mBase = 256 * ((br * (br + 3)) >> 1);
  const float* src = w + (size_t)f * Dn * k;
  int n = Dn * k;
  for (int e = threadIdx.x; e < n; e += 256) sf[e] = src[e];
  __syncthreads();
  for (int j = 0; j < k; ++j) {
    unsigned short* dst = Wp + (size_t)(mBase + j * 256 + f) * Dn;
    for (int d = threadIdx.x; d < Dn; d += 256) dst[d] = f2bf(sf[d * k + j]);
  }
}

// ---------------------------------------------------------------------------
// 3) packed-M conv-GEMM, counted-vmcnt pipeline, 1.5-set register pipelining:
//    B ring-4, write-ahead 3. Per step: issue B(s+3); read Af+Bhi in-step,
//    pre-read next step's Blo into the alternate reg set; MFMA Blo-group first
//    (ready) then Bhi-group (latency hidden under first 16 MFMAs).
// ---------------------------------------------------------------------------
static __device__ __forceinline__ void issueA(
    int d0i, char* sA, const char* const (&gA)[4], const char* gAt,
    int lane, int wvoff) {
  int aoff = (d0i + 1) * 64;
  char* nA = sA + ((d0i + 1) & 1) * ABUF;
  #pragma unroll
  for (int p = 0; p < 4; ++p) gload16(gA[p] + aoff, nA + p * 4096 + wvoff);
  if (lane < 16) gload16(gAt + aoff, nA + 16384);   // rows 256..259
}

static __device__ __forceinline__ void preBlo(
    const char* pB, int lrow, int lg, bf16x8 (&Bf)[4]) {
  #pragma unroll
  for (int n = 0; n < 4; ++n) {
    int row = n * 16 + lrow;
    Bf[n] = *(const bf16x8*)(pB + row * 64 + ((lg ^ ((row >> 1) & 3)) << 4));
  }
}

static __device__ __forceinline__ void domfma(
    bf16x8 (&Af)[4], bf16x8 (&Blo)[4], bf16x8 (&Bhi)[4], f32x4 (&acc)[4][8]) {
  __builtin_amdgcn_s_setprio(1);
  #pragma unroll
  for (int n = 0; n < 4; ++n)
    #pragma unroll
    for (int m = 0; m < 4; ++m)
      acc[m][n] = __builtin_amdgcn_mfma_f32_16x16x32_bf16(Af[m], Blo[n], acc[m][n], 0, 0, 0);
  #pragma unroll
  for (int n = 0; n < 4; ++n)
    #pragma unroll
    for (int m = 0; m < 4; ++m)
      acc[m][n + 4] = __builtin_amdgcn_mfma_f32_16x16x32_bf16(Af[m], Bhi[n], acc[m][n + 4], 0, 0, 0);
  __builtin_amdgcn_s_setprio(0);
}

template<int J, int W, int J3, int DADD3, int DOA, int SET, int AFIRST>
static __device__ __forceinline__ void step(
    int d0i, int bsl0, char* sA, char* sB,
    const char* const (&gA)[4], const char* gAt, const char* gB0,
    int lane, int wv, int lrow, int lg, int wvoff,
    bf16x8 (&Bp0)[4], bf16x8 (&Bp1)[4], f32x4 (&acc)[4][8]) {
  if constexpr (AFIRST && DOA) { if (d0i < 23) issueA(d0i, sA, gA, gAt, lane, wvoff); }
  {
    int dsl = (bsl0 + J + 3) & 3;
    int boff = J3 * JSTRIDE + (d0i + DADD3) * 64;
    char* bdst = sB + dsl * BSLOT + wvoff;
    gload16(gB0 + boff, bdst);
    gload16(gB0 + 98304 + boff, bdst + 4096);   // gB1 = gB0 + 64 rows (same swizzle)
  }
  if constexpr (DOA && !AFIRST) { if (d0i < 23) issueA(d0i, sA, gA, gAt, lane, wvoff); }
  // in-step ds_reads: Af (current d0), Bhi (current slot); pre-read next Blo
  const char* pA = sA + (d0i & 1) * ABUF;
  bf16x8 Af[4];
  #pragma unroll
  for (int m = 0; m < 4; ++m) {
    int row = wv * 64 + m * 16 + lrow + J;      // +J = the conv shift
    Af[m] = *(const bf16x8*)(pA + row * 64 + ((lg ^ ((row >> 1) & 3)) << 4));
  }
  const char* pBc = sB + ((bsl0 + J) & 3) * BSLOT;
  bf16x8 Bhi[4];
  #pragma unroll
  for (int n = 0; n < 4; ++n) {
    int row = (n + 4) * 16 + lrow;
    Bhi[n] = *(const bf16x8*)(pBc + row * 64 + ((lg ^ ((row >> 1) & 3)) << 4));
  }
  preBlo(sB + ((bsl0 + J + 1) & 3) * BSLOT, lrow, lg, sel<SET ^ 1>(Bp0, Bp1));
  domfma(Af, sel<SET>(Bp0, Bp1), Bhi, acc);
  __builtin_amdgcn_sched_barrier(0);
  waitv<W>();
  __builtin_amdgcn_sched_barrier(0);
  __builtin_amdgcn_s_barrier();
  __builtin_amdgcn_sched_barrier(0);
}

#define SA bsl0, sA, sB, gA, gAt, gB0, lane, wv, lrow, lg, wvoff, Bp0, Bp1, acc

template<int KK>
static __device__ __forceinline__ void conv_loop(
    char* sA, char* sB, const char* const (&gA)[4], const char* gAt,
    const char* gB0,
    int lane, int wv, int lrow, int lg, int wvoff, f32x4 (&acc)[4][8]) {
  bf16x8 Bp0[4], Bp1[4];
  // prologue: B slots 0,1,2 (= steps 0,1,2) + A(0); drain; pre-read Blo(0).
  gload16(gB0, sB + wvoff);
  gload16(gB0 + 98304, sB + 4096 + wvoff);
  gload16(gB0 + JSTRIDE, sB + BSLOT + wvoff);
  gload16(gB0 + 98304 + JSTRIDE, sB + BSLOT + 4096 + wvoff);
  constexpr int OFF2 = (KK >= 3) ? 2 * JSTRIDE : 64;   // step2 = (0,2) or (1,0)
  gload16(gB0 + OFF2, sB + 2 * BSLOT + wvoff);
  gload16(gB0 + 98304 + OFF2, sB + 2 * BSLOT + 4096 + wvoff);
  #pragma unroll
  for (int p = 0; p < 4; ++p) gload16(gA[p], sA + p * 4096 + wvoff);
  if (lane < 16) gload16(gAt, sA + 16384);
  waitv<0>();
  __builtin_amdgcn_s_barrier();
  preBlo(sB, lrow, lg, Bp0);

  int bsl0 = 0;
  if constexpr (KK == 5) {
    for (int dd = 0; dd < 22; dd += 2) {
      step<0,7,3,0,1, 0,0>(dd, SA);
      step<1,7,4,0,0, 1,0>(dd, SA);
      step<2,2,0,1,0, 0,0>(dd, SA);
      step<3,2,1,1,0, 1,0>(dd, SA);
      step<4,2,2,1,0, 0,0>(dd, SA);
      bsl0 = (bsl0 + 1) & 3;
      step<0,7,3,0,1, 1,0>(dd + 1, SA);
      step<1,7,4,0,0, 0,0>(dd + 1, SA);
      step<2,2,0,1,0, 1,0>(dd + 1, SA);
      step<3,2,1,1,0, 0,0>(dd + 1, SA);
      step<4,2,2,1,0, 1,0>(dd + 1, SA);
      bsl0 = (bsl0 + 1) & 3;
    }
    step<0,7,3,0,1, 0,0>(22, SA);
    step<1,7,4,0,0, 1,0>(22, SA);
    step<2,2,0,1,0, 0,0>(22, SA);
    step<3,2,1,1,0, 1,0>(22, SA);
    step<4,2,2,1,0, 0,0>(22, SA);
    bsl0 = (bsl0 + 1) & 3;
    step<0,2,3,0,0, 1,0>(23, SA);   // tail d0: no A issue, drain pace W=2
    step<1,2,4,0,0, 0,0>(23, SA);
    step<2,2,0,1,0, 1,0>(23, SA);
    step<3,2,1,1,0, 0,0>(23, SA);
    step<4,2,2,1,0, 1,0>(23, SA);
  } else if constexpr (KK == 4) {
    for (int dd = 0; dd < 23; ++dd) {
      step<0,7,3,0,1, 0,0>(dd, SA);
      step<1,7,0,1,0, 1,0>(dd, SA);
      step<2,2,1,1,0, 0,0>(dd, SA);
      step<3,2,2,1,0, 1,0>(dd, SA);
    }
    step<0,2,3,0,0, 0,0>(23, SA);
    step<1,2,0,1,0, 1,0>(23, SA);
    step<2,2,1,1,0, 0,0>(23, SA);
    step<3,2,2,1,0, 1,0>(23, SA);
  } else if constexpr (KK == 3) {
    for (int dd = 0; dd < 22; dd += 2) {
      step<0,7,0,1,1, 0,0>(dd, SA);
      step<1,7,1,1,0, 1,0>(dd, SA);
      step<2,2,2,1,0, 0,0>(dd, SA);
      bsl0 = (bsl0 + 3) & 3;
      step<0,7,0,1,1, 1,0>(dd + 1, SA);
      step<1,7,1,1,0, 0,0>(dd + 1, SA);
      step<2,2,2,1,0, 1,0>(dd + 1, SA);
      bsl0 = (bsl0 + 3) & 3;
    }
    step<0,7,0,1,1, 0,0>(22, SA);
    step<1,7,1,1,0, 1,0>(22, SA);
    step<2,2,2,1,0, 0,0>(22, SA);
    bsl0 = (bsl0 + 3) & 3;
    step<0,2,0,1,0, 1,0>(23, SA);
    step<1,2,1,1,0, 0,0>(23, SA);
    step<2,2,2,1,0, 1,0>(23, SA);
  } else {  // KK == 2, A issued first at j=0 (consumed 2 steps later)
    for (int dd = 0; dd < 23; ++dd) {
      step<0,7,1,1,1, 0,1>(dd, SA);
      step<1,2,0,2,0, 1,0>(dd, SA);
      bsl0 = (bsl0 + 2) & 3;
    }
    step<0,2,1,1,0, 0,0>(23, SA);
    step<1,2,0,2,0, 1,0>(23, SA);
  }
  waitv<0>();                       // no DMA may outlive this block's LDS
}

__global__ __launch_bounds__(256, 2) void conv_kernel(
    const unsigned short* __restrict__ hc, const unsigned short* __restrict__ Wp,
    const float* __restrict__ b2, const float* __restrict__ b3,
    const float* __restrict__ b4, const float* __restrict__ b5,
    const int* __restrict__ plan, const int* __restrict__ rowmap,
    int* __restrict__ feats) {
  __shared__ char smem[2 * ABUF + 4 * BSLOT];   // 66048 B -> 2 blocks/CU
  char* sA = smem;
  char* sB = smem + 2 * ABUF;
  int idx = blockIdx.x;
  // XCD-aware decode: tile ≡ xcd (mod 8) so all 8 subs of a tile share an XCD
  int xcd = idx & 7, s2 = idx >> 3;
  int sub = s2 & 7, tile = xcd + ((s2 >> 3) << 3);
  if (tile >= plan[0]) return;
  int br = 3 - (sub >> 1), ff = sub & 1, kk = br + 2;
  int mBase = 256 * ((br * (br + 3)) >> 1) + ff * 128;
  const float* bias = (br == 0) ? b2 : (br == 1) ? b3 : (br == 2) ? b4 : b5;
  int tid = threadIdx.x, lane = tid & 63, wv = tid >> 6;
  int lrow = lane & 15, lg = lane >> 4;
  int wvoff = wv * 1024;
  int P0 = tile << 8;

  // per-lane pre-swizzled global sources (d0-invariant)
  const char* gA[4];
  #pragma unroll
  for (int p = 0; p < 4; ++p) {
    int c = p * 256 + tid;
    int row = c >> 2, sgp = c & 3;
    int rm = rowmap[P0 + row];
    int bb_ = rm >> 20, t = rm & 1023;
    int seg = sgp ^ ((row >> 1) & 3);
    gA[p] = (const char*)(hc + ((size_t)(bb_ * SPn + t)) * Dn + seg * 8);
  }
  const char* gAt;
  {
    int l = lane & 15;               // rows 256..259 (only lanes<16 used)
    int row = 256 + (l >> 2), sgp = l & 3;
    int rm = rowmap[P0 + row];
    int bb_ = rm >> 20, t = rm & 1023;
    int seg = sgp ^ ((row >> 1) & 3);
    gAt = (const char*)(hc + ((size_t)(bb_ * SPn + t)) * Dn + seg * 8);
  }
  const char* gB0;
  {
    int row = tid >> 2, sgp = tid & 3;
    int seg = sgp ^ ((row >> 1) & 3);
    gB0 = (const char*)(Wp + ((size_t)(mBase + row)) * Dn + seg * 8);
  }

  f32x4 acc[4][8];
  #pragma unroll
  for (int m = 0; m < 4; ++m)
    #pragma unroll
    for (int n = 0; n < 8; ++n) acc[m][n] = (f32x4)0.f;

  switch (br) {
    case 3: conv_loop<5>(sA, sB, gA, gAt, gB0, lane, wv, lrow, lg, wvoff, acc); break;
    case 2: conv_loop<4>(sA, sB, gA, gAt, gB0, lane, wv, lrow, lg, wvoff, acc); break;
    case 1: conv_loop<3>(sA, sB, gA, gAt, gB0, lane, wv, lrow, lg, wvoff, acc); break;
    default: conv_loop<2>(sA, sB, gA, gAt, gB0, lane, wv, lrow, lg, wvoff, acc); break;
  }

  // epilogue: per m-fragment single batch; bias + mask + relu + pool + atomic
  int rmv[4];
  #pragma unroll
  for (int m = 0; m < 4; ++m) rmv[m] = rowmap[P0 + wv * 64 + m * 16];
  #pragma unroll
  for (int n = 0; n < 8; ++n) {
    int fg = ff * 128 + n * 16 + lrow;
    float bv = bias[fg];
    #pragma unroll
    for (int m = 0; m < 4; ++m) {
      int bb_ = rmv[m] >> 20;
      int Lb = (rmv[m] >> 10) & 1023;
      int t0 = (rmv[m] & 1023) + lg * 4;
      int vlim = Lb - kk + 1;
      float pmax = 0.f;
      #pragma unroll
      for (int i = 0; i < 4; ++i) {
        float v = acc[m][n][i] + bv;
        pmax = fmaxf(pmax, (t0 + i < vlim) ? fmaxf(v, 0.f) : 0.f);
      }
      pmax = fmaxf(pmax, __shfl_xor(pmax, 16));
      pmax = fmaxf(pmax, __shfl_xor(pmax, 32));
      if (lane < 16 && pmax > 0.f)
        atomicMax(feats + bb_ * 1024 + br * 256 + fg, __float_as_int(pmax));
    }
  }
}

// ---------------------------------------------------------------------------
// 4) FC + sigmoid
// ---------------------------------------------------------------------------
__global__ __launch_bounds__(64) void fc_kernel(
    const int* __restrict__ feats, const float* __restrict__ fcw,
    const float* __restrict__ fcb, float* __restrict__ out) {
  int b = blockIdx.x, lane = threadIdx.x;
  float acc = 0.f;
  for (int i = lane; i < 1024; i += 64)
    acc += __int_as_float(feats[b * 1024 + i]) * fcw[i];
  #pragma unroll
  for (int off = 32; off; off >>= 1) acc += __shfl_xor(acc, off);
  if (lane == 0) out[b] = 1.f / (1.f + expf(-(acc + fcb[0])));
}

extern "C" void kernel_launch(void* const* d_in, const int* in_sizes, int n_in,
                              void* d_out, int out_size, void* d_ws, size_t ws_size,
                              hipStream_t stream) {
  const int*   x   = (const int*)d_in[0];
  const float* h   = (const float*)d_in[1];
  const float* w2  = (const float*)d_in[2];
  const float* b2  = (const float*)d_in[3];
  const float* w3  = (const float*)d_in[4];
  const float* b3  = (const float*)d_in[5];
  const float* w4  = (const float*)d_in[6];
  const float* b4  = (const float*)d_in[7];
  const float* w5  = (const float*)d_in[8];
  const float* b5  = (const float*)d_in[9];
  const float* fcw = (const float*)d_in[10];
  const float* fcb = (const float*)d_in[11];
  float* out = (float*)d_out;
  char* ws = (char*)d_ws;
  unsigned short* hc = (unsigned short*)ws;               // 64*520*768*2 = 51,118,080
  unsigned short* Wp = (unsigned short*)(ws + 51118080);  // 3584*768*2   =  5,505,024
  int* feats  = (int*)(ws + 56623104);                    // 64*1024*4    =    262,144
  int* Lbuf   = (int*)(ws + 56885248);                    // 64*4
  int* plan   = (int*)(ws + 56885504);                    // 4 ints
  int* rowmap = (int*)(ws + 56885520);                    // (32768+264)*4

  hipMemsetAsync(feats, 0, 64 * 1024 * 4, stream);        // zero bits == 0.0f == relu floor
  compact_kernel<<<dim3(64, 8), 256, 0, stream>>>(x, h, hc, Lbuf);
  plan_kernel<<<1, 256, 0, stream>>>(Lbuf, plan, rowmap);
  wpack_kernel<<<1024, 256, 0, stream>>>(w2, w3, w4, w5, Wp);
  conv_kernel<<<1024, 256, 0, stream>>>(hc, Wp, b2, b3, b4, b5, plan, rowmap, feats);
  fc_kernel<<<64, 64, 0, stream>>>(feats, fcw, fcb, out);
}

// Round 8
// 115.838 us; speedup vs baseline: 2.3802x; 2.1922x over previous
//
#include <hip/hip_runtime.h>
#include <stdint.h>

#define Bn 64
#define Sn 512
#define SPn 520
#define Dn 768
#define JSTRIDE 196608   // 256 rows * 768 B : tap stride within wq
#define ABUF 16640       // 260 rows * 64 B
#define BSLOT 8192       // 128 rows * 64 B
#define QS_A 28.222222f  // 127/4.5
#define SAQ 0.035433072f // 4.5/127

typedef int iv4 __attribute__((ext_vector_type(4)));

static __device__ __forceinline__ signed char q8(float f, float s) {
  float t = __builtin_rintf(f * s);
  t = fmaxf(-127.f, fminf(127.f, t));
  return (signed char)(int)t;
}

// async global->LDS, 16B/lane; LDS dest = wave-uniform base + lane*16
static __device__ __forceinline__ void gload16(const void* g, void* l) {
  __builtin_amdgcn_global_load_lds(
      (const __attribute__((address_space(1))) unsigned int*)g,
      (__attribute__((address_space(3))) unsigned int*)l, 16, 0, 0);
}

template<int N> __device__ __forceinline__ void waitv() {
  static_assert(N == 0 || N == 2 || N == 7, "");
  if constexpr (N == 0) asm volatile("s_waitcnt vmcnt(0)" ::: "memory");
  else if constexpr (N == 2) asm volatile("s_waitcnt vmcnt(2)" ::: "memory");
  else asm volatile("s_waitcnt vmcnt(7)" ::: "memory");
}

// ---------------------------------------------------------------------------
// 1) stable compaction + f32->i8 quant (scale 127/4.5): hcq[b][t][d]
//    rows t>=L left stale (feed only masked outputs)
// ---------------------------------------------------------------------------
__global__ __launch_bounds__(256) void compact_kernel(
    const int* __restrict__ x, const float* __restrict__ h,
    signed char* __restrict__ hcq, int* __restrict__ Lout) {
  int b = blockIdx.x, rblk = blockIdx.y;
  __shared__ unsigned long long masks[8];
  __shared__ short sidx[Sn];
  int tid = threadIdx.x, lane = tid & 63, wv = tid >> 6;
  for (int c = wv; c < 8; c += 4) {
    bool pred = x[b * Sn + c * 64 + lane] != 0;
    unsigned long long m = __ballot(pred);
    if (lane == 0) masks[c] = m;
  }
  __syncthreads();
  int pref[9]; pref[0] = 0;
  #pragma unroll
  for (int c = 0; c < 8; ++c) pref[c + 1] = pref[c] + __popcll(masks[c]);
  int L = pref[8];
  for (int p = tid; p < Sn; p += 256) {
    int c = p >> 6, l = p & 63;
    unsigned long long m = masks[c];
    if ((m >> l) & 1ull)
      sidx[pref[c] + __popcll(m & ((1ull << l) - 1ull))] = (short)p;
  }
  if (rblk == 0 && tid == 0) Lout[b] = L;
  __syncthreads();
  int r0 = rblk * 65;  // 8 * 65 = 520 rows
  for (int r = r0 + wv; r < r0 + 65; r += 4) {
    if (r < L) {
      signed char* dst = hcq + ((size_t)b * SPn + r) * Dn;
      const float* src = h + ((size_t)b * Sn + sidx[r]) * Dn;
      #pragma unroll
      for (int c = 0; c < 3; ++c) {
        int d = c * 256 + lane * 4;
        float4 v = *(const float4*)(src + d);
        char4 o = { q8(v.x, QS_A), q8(v.y, QS_A), q8(v.z, QS_A), q8(v.w, QS_A) };
        *(char4*)(dst + d) = o;
      }
    }
  }
}

// ---------------------------------------------------------------------------
// 1.5) plan: 16-aligned per-batch segments packed densely; rowmap[p]=(b,L,t)
// ---------------------------------------------------------------------------
__global__ __launch_bounds__(256) void plan_kernel(
    const int* __restrict__ Lbuf, int* __restrict__ plan, int* __restrict__ rowmap) {
  __shared__ int sOff[65];
  __shared__ int sL[64];
  int tid = threadIdx.x;
  if (tid < 64) {
    int L = Lbuf[tid];
    int SL = (L + 15) & ~15;
    int pre = SL;
    #pragma unroll
    for (int off = 1; off < 64; off <<= 1) {
      int y = __shfl_up(pre, off);
      if (tid >= off) pre += y;
    }
    sOff[tid] = pre - SL;           // exclusive prefix
    sL[tid] = L;
    if (tid == 63) { sOff[64] = pre; plan[0] = (pre + 255) >> 8; }
  }
  __syncthreads();
  int M = sOff[64];
  for (int b = 0; b < 64; ++b) {
    int off = sOff[b], L = sL[b];
    int SL = (L + 15) & ~15;
    int enc = (b << 20) | (L << 10);
    for (int t = tid; t < SL; t += 256) rowmap[off + t] = enc | t;
  }
  for (int p = M + tid; p < M + 264; p += 256)
    rowmap[p] = 512;                // sentinel: b=0, L=0, t=512
}

// ---------------------------------------------------------------------------
// 2) weight repack + per-f int8 quant via LDS bounce.
//    wq[m][d], m = brOff + j*256 + f; fscale[br*256+f] = max|w[f]|/127
// ---------------------------------------------------------------------------
__global__ __launch_bounds__(256) void wpack_kernel(
    const float* __restrict__ w2, const float* __restrict__ w3,
    const float* __restrict__ w4, const float* __restrict__ w5,
    signed char* __restrict__ wq, float* __restrict__ fscale) {
  __shared__ float sf[3840];        // up to 768*5
  __shared__ float smax[4];
  int bb = blockIdx.x;
  int br = bb >> 8, f = bb & 255, k = br + 2;
  const float* w = (br == 0) ? w2 : (br == 1) ? w3 : (br == 2) ? w4 : w5;
  int mBase = 256 * ((br * (br + 3)) >> 1);
  const float* src = w + (size_t)f * Dn * k;
  int n = Dn * k;
  int tid = threadIdx.x, lane = tid & 63, wv = tid >> 6;
  float mx = 0.f;
  for (int e = tid; e < n; e += 256) {
    float v = src[e];
    sf[e] = v;
    mx = fmaxf(mx, fabsf(v));
  }
  #pragma unroll
  for (int off = 32; off; off >>= 1) mx = fmaxf(mx, __shfl_xor(mx, off));
  if (lane == 0) smax[wv] = mx;
  __syncthreads();
  float M = fmaxf(fmaxf(smax[0], smax[1]), fmaxf(smax[2], smax[3]));
  M = fmaxf(M, 1e-30f);
  if (tid == 0) fscale[br * 256 + f] = M / 127.f;
  float qs = 127.f / M;
  for (int j = 0; j < k; ++j) {
    signed char* dst = wq + (size_t)(mBase + j * 256 + f) * Dn;
    for (int d = tid; d < Dn; d += 256) dst[d] = q8(sf[d * k + j], qs);
  }
}

// ---------------------------------------------------------------------------
// 3) packed-M conv-GEMM, int8 16x16x64 MFMA, counted-vmcnt ring-3 pipeline
//    (round-5 schedule, d0 steps halved to 12; prologue FIFO order fixed)
// ---------------------------------------------------------------------------
static __device__ __forceinline__ void issueA(
    int d0i, char* sA, const char* const (&gA)[4], const char* gAt,
    int lane, int wvoff) {
  int aoff = (d0i + 1) * 64;
  char* nA = sA + ((d0i + 1) & 1) * ABUF;
  #pragma unroll
  for (int p = 0; p < 4; ++p) gload16(gA[p] + aoff, nA + p * 4096 + wvoff);
  if (lane < 16) gload16(gAt + aoff, nA + 16384);   // rows 256..259
}

template<int J, int W, int J2, int DADD, int DOA>
static __device__ __forceinline__ void conv_step(
    int d0i, int bsl0, char* sA, char* sB,
    const char* const (&gA)[4], const char* gAt, const char* gB0,
    int lane, int wv, int lrow, int lg, int wvoff, iv4 (&acc)[4][8]) {
  int sl = bsl0 + J;      sl  -= (sl  >= 3) ? 3 : 0; sl  -= (sl  >= 3) ? 3 : 0;
  int dsl = bsl0 + J + 2; dsl -= (dsl >= 3) ? 3 : 0; dsl -= (dsl >= 3) ? 3 : 0; dsl -= (dsl >= 3) ? 3 : 0;
  // stage issues (early): B(s+2), then A(d0i+1) at j==0
  {
    int boff = J2 * JSTRIDE + (d0i + DADD) * 64;
    char* bdst = sB + dsl * BSLOT + wvoff;
    gload16(gB0 + boff, bdst);
    gload16(gB0 + 49152 + boff, bdst + 4096);   // +64 rows (same swizzle class)
  }
  if constexpr (DOA) issueA(d0i, sA, gA, gAt, lane, wvoff);
  // ds_read fragments for this step
  const char* curA = sA + (d0i & 1) * ABUF;
  const char* curB = sB + sl * BSLOT;
  iv4 Af[4], Bf[8];
  #pragma unroll
  for (int m = 0; m < 4; ++m) {
    int row = wv * 64 + m * 16 + lrow + J;            // +J = the conv shift
    Af[m] = *(const iv4*)(curA + row * 64 + ((lg ^ ((row >> 1) & 3)) << 4));
  }
  #pragma unroll
  for (int n = 0; n < 8; ++n) {
    int row = n * 16 + lrow;
    Bf[n] = *(const iv4*)(curB + row * 64 + ((lg ^ ((row >> 1) & 3)) << 4));
  }
  __builtin_amdgcn_s_setprio(1);
  #pragma unroll
  for (int n = 0; n < 8; ++n)
    #pragma unroll
    for (int m = 0; m < 4; ++m)
      acc[m][n] = __builtin_amdgcn_mfma_i32_16x16x64_i8(Af[m], Bf[n], acc[m][n], 0, 0, 0);
  __builtin_amdgcn_s_setprio(0);
  __builtin_amdgcn_sched_barrier(0);
  waitv<W>();                       // counted: own loads for next step landed
  __builtin_amdgcn_sched_barrier(0);
  __builtin_amdgcn_s_barrier();     // whole next slot now valid for all waves
  __builtin_amdgcn_sched_barrier(0);
}

#define SA bsl0, sA, sB, gA, gAt, gB0, lane, wv, lrow, lg, wvoff, acc

template<int KK>
static __device__ __forceinline__ void conv_loop(
    char* sA, char* sB, const char* const (&gA)[4], const char* gAt,
    const char* gB0,
    int lane, int wv, int lrow, int lg, int wvoff, iv4 (&acc)[4][8]) {
  // prologue: A(0) FIRST (so waitv<2> retires all of A+B0), then B slots 0,1
  #pragma unroll
  for (int p = 0; p < 4; ++p) gload16(gA[p], sA + p * 4096 + wvoff);
  if (lane < 16) gload16(gAt, sA + 16384);
  gload16(gB0, sB + wvoff);
  gload16(gB0 + 49152, sB + 4096 + wvoff);
  gload16(gB0 + JSTRIDE, sB + BSLOT + wvoff);
  gload16(gB0 + 49152 + JSTRIDE, sB + BSLOT + 4096 + wvoff);
  __builtin_amdgcn_sched_barrier(0);
  waitv<2>();                       // A(0)+B(0) landed; B(1) may fly
  __builtin_amdgcn_sched_barrier(0);
  __builtin_amdgcn_s_barrier();
  __builtin_amdgcn_sched_barrier(0);
  int bsl0 = 0;
  for (int d0i = 0; d0i < 11; ++d0i) {
    if constexpr (KK == 5) {
      conv_step<0,7,2,0,1>(d0i, SA);
      conv_step<1,7,3,0,0>(d0i, SA);
      conv_step<2,2,4,0,0>(d0i, SA);
      conv_step<3,2,0,1,0>(d0i, SA);
      conv_step<4,2,1,1,0>(d0i, SA);
    } else if constexpr (KK == 4) {
      conv_step<0,7,2,0,1>(d0i, SA);
      conv_step<1,7,3,0,0>(d0i, SA);
      conv_step<2,2,0,1,0>(d0i, SA);
      conv_step<3,2,1,1,0>(d0i, SA);
    } else if constexpr (KK == 3) {
      conv_step<0,7,2,0,1>(d0i, SA);
      conv_step<1,7,0,1,0>(d0i, SA);
      conv_step<2,2,1,1,0>(d0i, SA);
    } else {
      conv_step<0,7,0,1,1>(d0i, SA);
      conv_step<1,2,1,1,0>(d0i, SA);
    }
    bsl0 += KK; bsl0 -= (bsl0 >= 3) ? 3 : 0; bsl0 -= (bsl0 >= 3) ? 3 : 0;
  }
  // tail d0 = 11: no A in FIFO -> all gates W=2; no A issue (DOA=0)
  if constexpr (KK == 5) {
    conv_step<0,2,2,0,0>(11, SA);
    conv_step<1,2,3,0,0>(11, SA);
    conv_step<2,2,4,0,0>(11, SA);
    conv_step<3,2,0,1,0>(11, SA);
    conv_step<4,2,1,1,0>(11, SA);
  } else if constexpr (KK == 4) {
    conv_step<0,2,2,0,0>(11, SA);
    conv_step<1,2,3,0,0>(11, SA);
    conv_step<2,2,0,1,0>(11, SA);
    conv_step<3,2,1,1,0>(11, SA);
  } else if constexpr (KK == 3) {
    conv_step<0,2,2,0,0>(11, SA);
    conv_step<1,2,0,1,0>(11, SA);
    conv_step<2,2,1,1,0>(11, SA);
  } else {
    conv_step<0,2,0,1,0>(11, SA);
    conv_step<1,2,1,1,0>(11, SA);
  }
  waitv<0>();                       // no DMA may outlive this block's LDS
}

__global__ __launch_bounds__(256, 2) void conv_kernel(
    const signed char* __restrict__ hcq, const signed char* __restrict__ wq,
    const float* __restrict__ b2, const float* __restrict__ b3,
    const float* __restrict__ b4, const float* __restrict__ b5,
    const float* __restrict__ fscale,
    const int* __restrict__ plan, const int* __restrict__ rowmap,
    int* __restrict__ feats) {
  __shared__ char smem[2 * ABUF + 3 * BSLOT];   // 57856 B -> 2 blocks/CU
  char* sA = smem;
  char* sB = smem + 2 * ABUF;
  int idx = blockIdx.x;
  // XCD-aware decode: tile ≡ xcd (mod 8) so all 8 subs of a tile share an XCD
  int xcd = idx & 7, s2 = idx >> 3;
  int sub = s2 & 7, tile = xcd + ((s2 >> 3) << 3);
  if (tile >= plan[0]) return;
  int br = 3 - (sub >> 1), ff = sub & 1, kk = br + 2;
  int mBase = 256 * ((br * (br + 3)) >> 1) + ff * 128;
  const float* bias = (br == 0) ? b2 : (br == 1) ? b3 : (br == 2) ? b4 : b5;
  int tid = threadIdx.x, lane = tid & 63, wv = tid >> 6;
  int lrow = lane & 15, lg = lane >> 4;
  int wvoff = wv * 1024;
  int P0 = tile << 8;

  // per-lane pre-swizzled global sources (d0-invariant)
  const char* gA[4];
  #pragma unroll
  for (int p = 0; p < 4; ++p) {
    int c = p * 256 + tid;
    int row = c >> 2, sgp = c & 3;
    int rm = rowmap[P0 + row];
    int bb_ = rm >> 20, t = rm & 1023;
    int seg = sgp ^ ((row >> 1) & 3);
    gA[p] = (const char*)(hcq + ((size_t)(bb_ * SPn + t)) * Dn + seg * 16);
  }
  const char* gAt;
  {
    int l = lane & 15;               // rows 256..259 (only lanes<16 used)
    int row = 256 + (l >> 2), sgp = l & 3;
    int rm = rowmap[P0 + row];
    int bb_ = rm >> 20, t = rm & 1023;
    int seg = sgp ^ ((row >> 1) & 3);
    gAt = (const char*)(hcq + ((size_t)(bb_ * SPn + t)) * Dn + seg * 16);
  }
  const char* gB0;
  {
    int row = tid >> 2, sgp = tid & 3;
    int seg = sgp ^ ((row >> 1) & 3);
    gB0 = (const char*)(wq + ((size_t)(mBase + row)) * Dn + seg * 16);
  }

  iv4 acc[4][8];
  #pragma unroll
  for (int m = 0; m < 4; ++m)
    #pragma unroll
    for (int n = 0; n < 8; ++n) acc[m][n] = (iv4)0;

  switch (br) {
    case 3: conv_loop<5>(sA, sB, gA, gAt, gB0, lane, wv, lrow, lg, wvoff, acc); break;
    case 2: conv_loop<4>(sA, sB, gA, gAt, gB0, lane, wv, lrow, lg, wvoff, acc); break;
    case 1: conv_loop<3>(sA, sB, gA, gAt, gB0, lane, wv, lrow, lg, wvoff, acc); break;
    default: conv_loop<2>(sA, sB, gA, gAt, gB0, lane, wv, lrow, lg, wvoff, acc); break;
  }

  // epilogue: dequant (s_a * s_f) + bias + mask + relu + pool + atomic
  int rmv[4];
  #pragma unroll
  for (int m = 0; m < 4; ++m) rmv[m] = rowmap[P0 + wv * 64 + m * 16];
  #pragma unroll
  for (int n = 0; n < 8; ++n) {
    int fg = ff * 128 + n * 16 + lrow;
    float bv = bias[fg];
    float sfc = fscale[br * 256 + fg] * SAQ;
    #pragma unroll
    for (int m = 0; m < 4; ++m) {
      int bb_ = rmv[m] >> 20;
      int Lb = (rmv[m] >> 10) & 1023;
      int t0 = (rmv[m] & 1023) + lg * 4;
      int vlim = Lb - kk + 1;
      float pmax = 0.f;
      #pragma unroll
      for (int i = 0; i < 4; ++i) {
        float v = (float)acc[m][n][i] * sfc + bv;
        pmax = fmaxf(pmax, (t0 + i < vlim) ? fmaxf(v, 0.f) : 0.f);
      }
      pmax = fmaxf(pmax, __shfl_xor(pmax, 16));
      pmax = fmaxf(pmax, __shfl_xor(pmax, 32));
      if (lane < 16 && pmax > 0.f)
        atomicMax(feats + bb_ * 1024 + br * 256 + fg, __float_as_int(pmax));
    }
  }
}

// ---------------------------------------------------------------------------
// 4) FC + sigmoid
// ---------------------------------------------------------------------------
__global__ __launch_bounds__(64) void fc_kernel(
    const int* __restrict__ feats, const float* __restrict__ fcw,
    const float* __restrict__ fcb, float* __restrict__ out) {
  int b = blockIdx.x, lane = threadIdx.x;
  float acc = 0.f;
  for (int i = lane; i < 1024; i += 64)
    acc += __int_as_float(feats[b * 1024 + i]) * fcw[i];
  #pragma unroll
  for (int off = 32; off; off >>= 1) acc += __shfl_xor(acc, off);
  if (lane == 0) out[b] = 1.f / (1.f + expf(-(acc + fcb[0])));
}

extern "C" void kernel_launch(void* const* d_in, const int* in_sizes, int n_in,
                              void* d_out, int out_size, void* d_ws, size_t ws_size,
                              hipStream_t stream) {
  const int*   x   = (const int*)d_in[0];
  const float* h   = (const float*)d_in[1];
  const float* w2  = (const float*)d_in[2];
  const float* b2  = (const float*)d_in[3];
  const float* w3  = (const float*)d_in[4];
  const float* b3  = (const float*)d_in[5];
  const float* w4  = (const float*)d_in[6];
  const float* b4  = (const float*)d_in[7];
  const float* w5  = (const float*)d_in[8];
  const float* b5  = (const float*)d_in[9];
  const float* fcw = (const float*)d_in[10];
  const float* fcb = (const float*)d_in[11];
  float* out = (float*)d_out;
  char* ws = (char*)d_ws;
  signed char* hcq = (signed char*)ws;                    // 64*520*768   = 25,559,040
  signed char* wq  = (signed char*)(ws + 25559040);       // 3584*768     =  2,752,512
  float* fscale = (float*)(ws + 28311552);                // 1024*4       =      4,096
  int* feats  = (int*)(ws + 28315648);                    // 64*1024*4    =    262,144
  int* Lbuf   = (int*)(ws + 28577792);                    // 64*4
  int* plan   = (int*)(ws + 28578048);                    // 4 ints
  int* rowmap = (int*)(ws + 28578064);                    // (32768+264)*4

  hipMemsetAsync(feats, 0, 64 * 1024 * 4, stream);        // zero bits == 0.0f == relu floor
  compact_kernel<<<dim3(64, 8), 256, 0, stream>>>(x, h, hcq, Lbuf);
  plan_kernel<<<1, 256, 0, stream>>>(Lbuf, plan, rowmap);
  wpack_kernel<<<1024, 256, 0, stream>>>(w2, w3, w4, w5, wq, fscale);
  conv_kernel<<<1024, 256, 0, stream>>>(hcq, wq, b2, b3, b4, b5, fscale, plan, rowmap, feats);
  fc_kernel<<<64, 64, 0, stream>>>(feats, fcw, fcb, out);
}

// Round 9
// 115.177 us; speedup vs baseline: 2.3938x; 1.0057x over previous
//
#include <hip/hip_runtime.h>
#include <stdint.h>

#define Bn 64
#define Sn 512
#define SPn 520
#define Dn 768
#define JSTRIDE 196608   // 256 rows * 768 B : tap stride within wq
#define ABUF 16640       // 260 rows * 64 B
#define BSLOT 8192       // 128 rows * 64 B
#define QS_A 28.222222f  // 127/4.5
#define SAQ 0.035433072f // 4.5/127

typedef int iv4 __attribute__((ext_vector_type(4)));

static __device__ __forceinline__ signed char q8(float f, float s) {
  float t = __builtin_rintf(f * s);
  t = fmaxf(-127.f, fminf(127.f, t));
  return (signed char)(int)t;
}

// async global->LDS, 16B/lane; LDS dest = wave-uniform base + lane*16
static __device__ __forceinline__ void gload16(const void* g, void* l) {
  __builtin_amdgcn_global_load_lds(
      (const __attribute__((address_space(1))) unsigned int*)g,
      (__attribute__((address_space(3))) unsigned int*)l, 16, 0, 0);
}

template<int N> __device__ __forceinline__ void waitv() {
  static_assert(N == 0 || N == 1 || N == 4, "");
  if constexpr (N == 0) asm volatile("s_waitcnt vmcnt(0)" ::: "memory");
  else if constexpr (N == 1) asm volatile("s_waitcnt vmcnt(1)" ::: "memory");
  else asm volatile("s_waitcnt vmcnt(4)" ::: "memory");
}

// ---------------------------------------------------------------------------
// 1) plan: computes L from x directly; 16-aligned segments packed densely;
//    rowmap[p] = (b<<20)|(L<<10)|t
// ---------------------------------------------------------------------------
__global__ __launch_bounds__(256) void plan_kernel(
    const int* __restrict__ x, int* __restrict__ plan, int* __restrict__ rowmap) {
  __shared__ int sL[64];
  __shared__ int sOff[65];
  int tid = threadIdx.x, lane = tid & 63, wv = tid >> 6;
  for (int bb = wv; bb < 64; bb += 4) {
    int cnt = 0;
    for (int c = 0; c < 8; ++c) {
      unsigned long long m = __ballot(x[bb * Sn + c * 64 + lane] != 0);
      cnt += __popcll(m);
    }
    if (lane == 0) sL[bb] = cnt;
  }
  __syncthreads();
  if (tid < 64) {
    int L = sL[tid];
    int SL = (L + 15) & ~15;
    int pre = SL;
    #pragma unroll
    for (int off = 1; off < 64; off <<= 1) {
      int y = __shfl_up(pre, off);
      if (tid >= off) pre += y;
    }
    sOff[tid] = pre - SL;           // exclusive prefix
    if (tid == 63) { sOff[64] = pre; plan[0] = (pre + 255) >> 8; }
  }
  __syncthreads();
  int M = sOff[64];
  for (int b = 0; b < 64; ++b) {
    int off = sOff[b], L = sL[b];
    int SL = (L + 15) & ~15;
    int enc = (b << 20) | (L << 10);
    for (int t = tid; t < SL; t += 256) rowmap[off + t] = enc | t;
  }
  for (int p = M + tid; p < M + 264; p += 256)
    rowmap[p] = 512;                // sentinel: b=0, L=0, t=512
}

// ---------------------------------------------------------------------------
// 2) fused stage: blocks [0,512) compact+quant h -> hcq; [512,1536) wpack
// ---------------------------------------------------------------------------
__global__ __launch_bounds__(256) void stage_kernel(
    const int* __restrict__ x, const float* __restrict__ h,
    const float* __restrict__ w2, const float* __restrict__ w3,
    const float* __restrict__ w4, const float* __restrict__ w5,
    signed char* __restrict__ hcq, signed char* __restrict__ wq,
    float* __restrict__ fscale) {
  int tid = threadIdx.x, lane = tid & 63, wv = tid >> 6;
  if (blockIdx.x < 512) {
    // ---- compact: stable compaction + f32->i8 quant; rows t>=L left stale
    int cidx = blockIdx.x;
    int b = cidx >> 3, rblk = cidx & 7;
    __shared__ unsigned long long masks[8];
    __shared__ short sidx[Sn];
    for (int c = wv; c < 8; c += 4) {
      unsigned long long m = __ballot(x[b * Sn + c * 64 + lane] != 0);
      if (lane == 0) masks[c] = m;
    }
    __syncthreads();
    int pref[9]; pref[0] = 0;
    #pragma unroll
    for (int c = 0; c < 8; ++c) pref[c + 1] = pref[c] + __popcll(masks[c]);
    int L = pref[8];
    for (int p = tid; p < Sn; p += 256) {
      int c = p >> 6, l = p & 63;
      unsigned long long m = masks[c];
      if ((m >> l) & 1ull)
        sidx[pref[c] + __popcll(m & ((1ull << l) - 1ull))] = (short)p;
    }
    __syncthreads();
    int r0 = rblk * 65;  // 8 * 65 = 520 rows
    for (int r = r0 + wv; r < r0 + 65; r += 4) {
      if (r < L) {
        signed char* dst = hcq + ((size_t)b * SPn + r) * Dn;
        const float* src = h + ((size_t)b * Sn + sidx[r]) * Dn;
        #pragma unroll
        for (int c = 0; c < 3; ++c) {
          int d = c * 256 + lane * 4;
          float4 v = *(const float4*)(src + d);
          char4 o = { q8(v.x, QS_A), q8(v.y, QS_A), q8(v.z, QS_A), q8(v.w, QS_A) };
          *(char4*)(dst + d) = o;
        }
      }
    }
  } else {
    // ---- wpack: weight repack + per-f int8 quant via LDS bounce
    __shared__ float sf[3840];
    __shared__ float smax[4];
    int bb = blockIdx.x - 512;
    int br = bb >> 8, f = bb & 255, k = br + 2;
    const float* w = (br == 0) ? w2 : (br == 1) ? w3 : (br == 2) ? w4 : w5;
    int mBase = 256 * ((br * (br + 3)) >> 1);
    const float* src = w + (size_t)f * Dn * k;
    int n = Dn * k;
    float mx = 0.f;
    for (int e = tid; e < n; e += 256) {
      float v = src[e];
      sf[e] = v;
      mx = fmaxf(mx, fabsf(v));
    }
    #pragma unroll
    for (int off = 32; off; off >>= 1) mx = fmaxf(mx, __shfl_xor(mx, off));
    if (lane == 0) smax[wv] = mx;
    __syncthreads();
    float M = fmaxf(fmaxf(smax[0], smax[1]), fmaxf(smax[2], smax[3]));
    M = fmaxf(M, 1e-30f);
    if (tid == 0) fscale[br * 256 + f] = M / 127.f;
    float qs = 127.f / M;
    for (int j = 0; j < k; ++j) {
      signed char* dst = wq + (size_t)(mBase + j * 256 + f) * Dn;
      for (int d = tid; d < Dn; d += 256) dst[d] = q8(sf[d * k + j], qs);
    }
  }
}

// ---------------------------------------------------------------------------
// 3) packed-M conv-GEMM, int8 16x16x64 MFMA, 8 waves (wave tile 64t x 64f),
//    counted-vmcnt ring-3 pipeline. Per wave per step: 1 B gload (+3 A at j0),
//    8 ds_read_b128, 16 MFMA. W inventory: {4,4,1,...} per d0, tail all 1.
// ---------------------------------------------------------------------------
static __device__ __forceinline__ void issueA(
    int d0i, char* sA, const char* const (&gA)[2], const char* gAt,
    int lane, int wvoff) {
  int aoff = (d0i + 1) * 64;
  char* nA = sA + ((d0i + 1) & 1) * ABUF;
  #pragma unroll
  for (int p = 0; p < 2; ++p) gload16(gA[p] + aoff, nA + p * 8192 + wvoff);
  if (lane < 16) gload16(gAt + aoff, nA + 16384);   // rows 256..259 (all waves dup)
}

template<int J, int W, int J2, int DADD, int DOA>
static __device__ __forceinline__ void conv_step(
    int d0i, int bsl0, char* sA, char* sB,
    const char* const (&gA)[2], const char* gAt, const char* gB0,
    int lane, int wr, int wc, int lrow, int lg, int wvoff, iv4 (&acc)[4][4]) {
  int sl = bsl0 + J;      sl  -= (sl  >= 3) ? 3 : 0; sl  -= (sl  >= 3) ? 3 : 0;
  int dsl = bsl0 + J + 2; dsl -= (dsl >= 3) ? 3 : 0; dsl -= (dsl >= 3) ? 3 : 0;
  // stage issues (early): B(s+2), then A(d0i+1) at j==0
  {
    int boff = J2 * JSTRIDE + (d0i + DADD) * 64;
    gload16(gB0 + boff, sB + dsl * BSLOT + wvoff);
  }
  if constexpr (DOA) issueA(d0i, sA, gA, gAt, lane, wvoff);
  // ds_read fragments for this step
  const char* curA = sA + (d0i & 1) * ABUF;
  const char* curB = sB + sl * BSLOT;
  iv4 Af[4], Bf[4];
  #pragma unroll
  for (int m = 0; m < 4; ++m) {
    int row = wr * 64 + m * 16 + lrow + J;            // +J = the conv shift
    Af[m] = *(const iv4*)(curA + row * 64 + ((lg ^ ((row >> 1) & 3)) << 4));
  }
  #pragma unroll
  for (int n = 0; n < 4; ++n) {
    int row = wc * 64 + n * 16 + lrow;
    Bf[n] = *(const iv4*)(curB + row * 64 + ((lg ^ ((row >> 1) & 3)) << 4));
  }
  __builtin_amdgcn_s_setprio(1);
  #pragma unroll
  for (int n = 0; n < 4; ++n)
    #pragma unroll
    for (int m = 0; m < 4; ++m)
      acc[m][n] = __builtin_amdgcn_mfma_i32_16x16x64_i8(Af[m], Bf[n], acc[m][n], 0, 0, 0);
  __builtin_amdgcn_s_setprio(0);
  __builtin_amdgcn_sched_barrier(0);
  waitv<W>();                       // counted: own loads for next step landed
  __builtin_amdgcn_sched_barrier(0);
  __builtin_amdgcn_s_barrier();     // whole next slot now valid for all waves
  __builtin_amdgcn_sched_barrier(0);
}

#define SA bsl0, sA, sB, gA, gAt, gB0, lane, wr, wc, lrow, lg, wvoff, acc

template<int KK>
static __device__ __forceinline__ void conv_loop(
    char* sA, char* sB, const char* const (&gA)[2], const char* gAt,
    const char* gB0,
    int lane, int wr, int wc, int lrow, int lg, int wvoff, iv4 (&acc)[4][4]) {
  // prologue: A(0) first, then B slot0 (tap0), slot1 (tap1). FIFO: [A,A,At,B0,B1]
  #pragma unroll
  for (int p = 0; p < 2; ++p) gload16(gA[p], sA + p * 8192 + wvoff);
  if (lane < 16) gload16(gAt, sA + 16384);
  gload16(gB0, sB + wvoff);
  gload16(gB0 + JSTRIDE, sB + BSLOT + wvoff);
  __builtin_amdgcn_sched_barrier(0);
  waitv<1>();                       // A(0)+B(0) landed; B(1) may fly
  __builtin_amdgcn_sched_barrier(0);
  __builtin_amdgcn_s_barrier();
  __builtin_amdgcn_sched_barrier(0);
  int bsl0 = 0;
  for (int d0i = 0; d0i < 11; ++d0i) {
    if constexpr (KK == 5) {
      conv_step<0,4,2,0,1>(d0i, SA);
      conv_step<1,4,3,0,0>(d0i, SA);
      conv_step<2,1,4,0,0>(d0i, SA);
      conv_step<3,1,0,1,0>(d0i, SA);
      conv_step<4,1,1,1,0>(d0i, SA);
    } else if constexpr (KK == 4) {
      conv_step<0,4,2,0,1>(d0i, SA);
      conv_step<1,4,3,0,0>(d0i, SA);
      conv_step<2,1,0,1,0>(d0i, SA);
      conv_step<3,1,1,1,0>(d0i, SA);
    } else if constexpr (KK == 3) {
      conv_step<0,4,2,0,1>(d0i, SA);
      conv_step<1,4,0,1,0>(d0i, SA);
      conv_step<2,1,1,1,0>(d0i, SA);
    } else {
      conv_step<0,4,0,1,1>(d0i, SA);
      conv_step<1,1,1,1,0>(d0i, SA);
    }
    bsl0 += KK; bsl0 -= (bsl0 >= 3) ? 3 : 0; bsl0 -= (bsl0 >= 3) ? 3 : 0;
  }
  // tail d0 = 11: no A issue; all gates W=1 (only B pairs in FIFO)
  if constexpr (KK == 5) {
    conv_step<0,1,2,0,0>(11, SA);
    conv_step<1,1,3,0,0>(11, SA);
    conv_step<2,1,4,0,0>(11, SA);
    conv_step<3,1,0,1,0>(11, SA);
    conv_step<4,1,1,1,0>(11, SA);
  } else if constexpr (KK == 4) {
    conv_step<0,1,2,0,0>(11, SA);
    conv_step<1,1,3,0,0>(11, SA);
    conv_step<2,1,0,1,0>(11, SA);
    conv_step<3,1,1,1,0>(11, SA);
  } else if constexpr (KK == 3) {
    conv_step<0,1,2,0,0>(11, SA);
    conv_step<1,1,0,1,0>(11, SA);
    conv_step<2,1,1,1,0>(11, SA);
  } else {
    conv_step<0,1,0,1,0>(11, SA);
    conv_step<1,1,1,1,0>(11, SA);
  }
  waitv<0>();                       // no DMA may outlive this block's LDS
}

__global__ __launch_bounds__(512, 4) void conv_kernel(
    const signed char* __restrict__ hcq, const signed char* __restrict__ wq,
    const float* __restrict__ b2, const float* __restrict__ b3,
    const float* __restrict__ b4, const float* __restrict__ b5,
    const float* __restrict__ fscale,
    const int* __restrict__ plan, const int* __restrict__ rowmap,
    int* __restrict__ feats) {
  __shared__ char smem[2 * ABUF + 3 * BSLOT];   // 57856 B -> 2 blocks/CU (16 waves)
  char* sA = smem;
  char* sB = smem + 2 * ABUF;
  int idx = blockIdx.x;
  // XCD-aware decode: tile ≡ xcd (mod 8) so all 8 subs of a tile share an XCD
  int xcd = idx & 7, s2 = idx >> 3;
  int sub = s2 & 7, tile = xcd + ((s2 >> 3) << 3);
  if (tile >= plan[0]) return;
  int br = 3 - (sub >> 1), ff = sub & 1, kk = br + 2;
  int mBase = 256 * ((br * (br + 3)) >> 1) + ff * 128;
  const float* bias = (br == 0) ? b2 : (br == 1) ? b3 : (br == 2) ? b4 : b5;
  int tid = threadIdx.x, lane = tid & 63, wv = tid >> 6;
  int wr = wv >> 1, wc = wv & 1;     // wave tile: 64t x 64f
  int lrow = lane & 15, lg = lane >> 4;
  int wvoff = wv * 1024;
  int P0 = tile << 8;

  // per-lane pre-swizzled global sources (d0-invariant)
  const char* gA[2];
  #pragma unroll
  for (int p = 0; p < 2; ++p) {
    int c = p * 512 + tid;
    int row = c >> 2, sgp = c & 3;
    int rm = rowmap[P0 + row];
    int bb_ = rm >> 20, t = rm & 1023;
    int seg = sgp ^ ((row >> 1) & 3);
    gA[p] = (const char*)(hcq + ((size_t)(bb_ * SPn + t)) * Dn + seg * 16);
  }
  const char* gAt;
  {
    int l = lane & 15;               // rows 256..259 (lanes<16, all waves dup)
    int row = 256 + (l >> 2), sgp = l & 3;
    int rm = rowmap[P0 + row];
    int bb_ = rm >> 20, t = rm & 1023;
    int seg = sgp ^ ((row >> 1) & 3);
    gAt = (const char*)(hcq + ((size_t)(bb_ * SPn + t)) * Dn + seg * 16);
  }
  const char* gB0;
  {
    int row = tid >> 2, sgp = tid & 3;   // 512 chunks = 128 rows x 4 segs
    int seg = sgp ^ ((row >> 1) & 3);
    gB0 = (const char*)(wq + ((size_t)(mBase + row)) * Dn + seg * 16);
  }

  iv4 acc[4][4];
  #pragma unroll
  for (int m = 0; m < 4; ++m)
    #pragma unroll
    for (int n = 0; n < 4; ++n) acc[m][n] = (iv4)0;

  switch (br) {
    case 3: conv_loop<5>(sA, sB, gA, gAt, gB0, lane, wr, wc, lrow, lg, wvoff, acc); break;
    case 2: conv_loop<4>(sA, sB, gA, gAt, gB0, lane, wr, wc, lrow, lg, wvoff, acc); break;
    case 1: conv_loop<3>(sA, sB, gA, gAt, gB0, lane, wr, wc, lrow, lg, wvoff, acc); break;
    default: conv_loop<2>(sA, sB, gA, gAt, gB0, lane, wr, wc, lrow, lg, wvoff, acc); break;
  }

  // epilogue: dequant (s_a * s_f) + bias + mask + relu + pool + atomic
  int rmv[4];
  #pragma unroll
  for (int m = 0; m < 4; ++m) rmv[m] = rowmap[P0 + wr * 64 + m * 16];
  #pragma unroll
  for (int n = 0; n < 4; ++n) {
    int fg = ff * 128 + wc * 64 + n * 16 + lrow;
    float bv = bias[fg];
    float sfc = fscale[br * 256 + fg] * SAQ;
    #pragma unroll
    for (int m = 0; m < 4; ++m) {
      int bb_ = rmv[m] >> 20;
      int Lb = (rmv[m] >> 10) & 1023;
      int t0 = (rmv[m] & 1023) + lg * 4;
      int vlim = Lb - kk + 1;
      float pmax = 0.f;
      #pragma unroll
      for (int i = 0; i < 4; ++i) {
        float v = (float)acc[m][n][i] * sfc + bv;
        pmax = fmaxf(pmax, (t0 + i < vlim) ? fmaxf(v, 0.f) : 0.f);
      }
      pmax = fmaxf(pmax, __shfl_xor(pmax, 16));
      pmax = fmaxf(pmax, __shfl_xor(pmax, 32));
      if (lane < 16 && pmax > 0.f)
        atomicMax(feats + bb_ * 1024 + br * 256 + fg, __float_as_int(pmax));
    }
  }
}

// ---------------------------------------------------------------------------
// 4) FC + sigmoid
// ---------------------------------------------------------------------------
__global__ __launch_bounds__(64) void fc_kernel(
    const int* __restrict__ feats, const float* __restrict__ fcw,
    const float* __restrict__ fcb, float* __restrict__ out) {
  int b = blockIdx.x, lane = threadIdx.x;
  float acc = 0.f;
  for (int i = lane; i < 1024; i += 64)
    acc += __int_as_float(feats[b * 1024 + i]) * fcw[i];
  #pragma unroll
  for (int off = 32; off; off >>= 1) acc += __shfl_xor(acc, off);
  if (lane == 0) out[b] = 1.f / (1.f + expf(-(acc + fcb[0])));
}

extern "C" void kernel_launch(void* const* d_in, const int* in_sizes, int n_in,
                              void* d_out, int out_size, void* d_ws, size_t ws_size,
                              hipStream_t stream) {
  const int*   x   = (const int*)d_in[0];
  const float* h   = (const float*)d_in[1];
  const float* w2  = (const float*)d_in[2];
  const float* b2  = (const float*)d_in[3];
  const float* w3  = (const float*)d_in[4];
  const float* b3  = (const float*)d_in[5];
  const float* w4  = (const float*)d_in[6];
  const float* b4  = (const float*)d_in[7];
  const float* w5  = (const float*)d_in[8];
  const float* b5  = (const float*)d_in[9];
  const float* fcw = (const float*)d_in[10];
  const float* fcb = (const float*)d_in[11];
  float* out = (float*)d_out;
  char* ws = (char*)d_ws;
  signed char* hcq = (signed char*)ws;                    // 64*520*768   = 25,559,040
  signed char* wq  = (signed char*)(ws + 25559040);       // 3584*768     =  2,752,512
  float* fscale = (float*)(ws + 28311552);                // 1024*4
  int* feats  = (int*)(ws + 28315648);                    // 64*1024*4    =    262,144
  int* plan   = (int*)(ws + 28577792);                    // 4 ints
  int* rowmap = (int*)(ws + 28577808);                    // (32768+264)*4

  hipMemsetAsync(feats, 0, 64 * 1024 * 4, stream);        // zero bits == 0.0f == relu floor
  plan_kernel<<<1, 256, 0, stream>>>(x, plan, rowmap);
  stage_kernel<<<1536, 256, 0, stream>>>(x, h, w2, w3, w4, w5, hcq, wq, fscale);
  conv_kernel<<<1024, 512, 0, stream>>>(hcq, wq, b2, b3, b4, b5, fscale, plan, rowmap, feats);
  fc_kernel<<<64, 64, 0, stream>>>(feats, fcw, fcb, out);
}

// Round 10
// 110.605 us; speedup vs baseline: 2.4928x; 1.0413x over previous
//
#include <hip/hip_runtime.h>
#include <stdint.h>

#define Bn 64
#define Sn 512
#define SPn 520
#define Dn 768
#define JSTRIDE 196608   // 256 rows * 768 B : tap stride within wq
#define ABUF 16640       // 260 rows * 64 B
#define BSLOT 8192       // 128 rows * 64 B
#define QS_A 28.222222f  // 127/4.5
#define SAQ 0.035433072f // 4.5/127

typedef int iv4 __attribute__((ext_vector_type(4)));

static __device__ __forceinline__ signed char q8(float f, float s) {
  float t = __builtin_rintf(f * s);
  t = fmaxf(-127.f, fminf(127.f, t));
  return (signed char)(int)t;
}

// async global->LDS, 16B/lane; LDS dest = wave-uniform base + lane*16
static __device__ __forceinline__ void gload16(const void* g, void* l) {
  __builtin_amdgcn_global_load_lds(
      (const __attribute__((address_space(1))) unsigned int*)g,
      (__attribute__((address_space(3))) unsigned int*)l, 16, 0, 0);
}

template<int N> __device__ __forceinline__ void waitv() {
  static_assert(N == 0 || N == 1 || N == 4, "");
  if constexpr (N == 0) asm volatile("s_waitcnt vmcnt(0)" ::: "memory");
  else if constexpr (N == 1) asm volatile("s_waitcnt vmcnt(1)" ::: "memory");
  else asm volatile("s_waitcnt vmcnt(4)" ::: "memory");
}

template<int S, typename T, int N>
static __device__ __forceinline__ T (&sel(T (&a)[N], T (&b)[N]))[N] {
  if constexpr (S) return b; else return a;
}

// ---------------------------------------------------------------------------
// 1) plan: L from x; 16-aligned segments packed densely; rowmap=(b,L,t);
//    also zeroes feats (relu floor)
// ---------------------------------------------------------------------------
__global__ __launch_bounds__(256) void plan_kernel(
    const int* __restrict__ x, int* __restrict__ plan, int* __restrict__ rowmap,
    int* __restrict__ feats) {
  __shared__ int sL[64];
  __shared__ int sOff[65];
  int tid = threadIdx.x, lane = tid & 63, wv = tid >> 6;
  {
    int4 z = {0, 0, 0, 0};
    for (int i = tid * 4; i < 65536; i += 1024) *(int4*)(feats + i) = z;
  }
  for (int bb = wv; bb < 64; bb += 4) {
    int cnt = 0;
    for (int c = 0; c < 8; ++c) {
      unsigned long long m = __ballot(x[bb * Sn + c * 64 + lane] != 0);
      cnt += __popcll(m);
    }
    if (lane == 0) sL[bb] = cnt;
  }
  __syncthreads();
  if (tid < 64) {
    int L = sL[tid];
    int SL = (L + 15) & ~15;
    int pre = SL;
    #pragma unroll
    for (int off = 1; off < 64; off <<= 1) {
      int y = __shfl_up(pre, off);
      if (tid >= off) pre += y;
    }
    sOff[tid] = pre - SL;           // exclusive prefix
    if (tid == 63) { sOff[64] = pre; plan[0] = (pre + 255) >> 8; }
  }
  __syncthreads();
  int M = sOff[64];
  for (int b = 0; b < 64; ++b) {
    int off = sOff[b], L = sL[b];
    int SL = (L + 15) & ~15;
    int enc = (b << 20) | (L << 10);
    for (int t = tid; t < SL; t += 256) rowmap[off + t] = enc | t;
  }
  for (int p = M + tid; p < M + 264; p += 256)
    rowmap[p] = 512;                // sentinel: b=0, L=0, t=512
}

// ---------------------------------------------------------------------------
// 2) fused stage: blocks [0,512) compact+quant h -> hcq; [512,1536) wpack
// ---------------------------------------------------------------------------
__global__ __launch_bounds__(256) void stage_kernel(
    const int* __restrict__ x, const float* __restrict__ h,
    const float* __restrict__ w2, const float* __restrict__ w3,
    const float* __restrict__ w4, const float* __restrict__ w5,
    signed char* __restrict__ hcq, signed char* __restrict__ wq,
    float* __restrict__ fscale) {
  int tid = threadIdx.x, lane = tid & 63, wv = tid >> 6;
  if (blockIdx.x < 512) {
    int cidx = blockIdx.x;
    int b = cidx >> 3, rblk = cidx & 7;
    __shared__ unsigned long long masks[8];
    __shared__ short sidx[Sn];
    for (int c = wv; c < 8; c += 4) {
      unsigned long long m = __ballot(x[b * Sn + c * 64 + lane] != 0);
      if (lane == 0) masks[c] = m;
    }
    __syncthreads();
    int pref[9]; pref[0] = 0;
    #pragma unroll
    for (int c = 0; c < 8; ++c) pref[c + 1] = pref[c] + __popcll(masks[c]);
    int L = pref[8];
    for (int p = tid; p < Sn; p += 256) {
      int c = p >> 6, l = p & 63;
      unsigned long long m = masks[c];
      if ((m >> l) & 1ull)
        sidx[pref[c] + __popcll(m & ((1ull << l) - 1ull))] = (short)p;
    }
    __syncthreads();
    int r0 = rblk * 65;  // 8 * 65 = 520 rows
    for (int r = r0 + wv; r < r0 + 65; r += 4) {
      if (r < L) {
        signed char* dst = hcq + ((size_t)b * SPn + r) * Dn;
        const float* src = h + ((size_t)b * Sn + sidx[r]) * Dn;
        #pragma unroll
        for (int c = 0; c < 3; ++c) {
          int d = c * 256 + lane * 4;
          float4 v = *(const float4*)(src + d);
          char4 o = { q8(v.x, QS_A), q8(v.y, QS_A), q8(v.z, QS_A), q8(v.w, QS_A) };
          *(char4*)(dst + d) = o;
        }
      }
    }
  } else {
    __shared__ float sf[3840];
    __shared__ float smax[4];
    int bb = blockIdx.x - 512;
    int br = bb >> 8, f = bb & 255, k = br + 2;
    const float* w = (br == 0) ? w2 : (br == 1) ? w3 : (br == 2) ? w4 : w5;
    int mBase = 256 * ((br * (br + 3)) >> 1);
    const float* src = w + (size_t)f * Dn * k;
    int n = Dn * k;
    float mx = 0.f;
    for (int e = tid; e < n; e += 256) {
      float v = src[e];
      sf[e] = v;
      mx = fmaxf(mx, fabsf(v));
    }
    #pragma unroll
    for (int off = 32; off; off >>= 1) mx = fmaxf(mx, __shfl_xor(mx, off));
    if (lane == 0) smax[wv] = mx;
    __syncthreads();
    float M = fmaxf(fmaxf(smax[0], smax[1]), fmaxf(smax[2], smax[3]));
    M = fmaxf(M, 1e-30f);
    if (tid == 0) fscale[br * 256 + f] = M / 127.f;
    float qs = 127.f / M;
    for (int j = 0; j < k; ++j) {
      signed char* dst = wq + (size_t)(mBase + j * 256 + f) * Dn;
      for (int d4 = tid * 4; d4 < Dn; d4 += 1024) {
        char4 o = { q8(sf[(d4 + 0) * k + j], qs), q8(sf[(d4 + 1) * k + j], qs),
                    q8(sf[(d4 + 2) * k + j], qs), q8(sf[(d4 + 3) * k + j], qs) };
        *(char4*)(dst + d4) = o;
      }
    }
  }
}

// ---------------------------------------------------------------------------
// 3) packed-M conv-GEMM, int8 16x16x64, 8 waves (64t x 64f each),
//    ring-4 B slots (write-ahead 3) + register pre-read pipeline:
//    step s: issue B(s+3); pre-read s+1 fragments (slot guaranteed by the
//    PREVIOUS gate) into alternate reg set; MFMA current set (no LDS dep);
//    counted waitv; raw barrier. ds_read latency crosses the barrier.
// ---------------------------------------------------------------------------
static __device__ __forceinline__ void issueA(
    int d0i, char* sA, const char* const (&gA)[2], const char* gAt,
    int lane, int wvoff) {
  int aoff = (d0i + 1) * 64;
  char* nA = sA + ((d0i + 1) & 1) * ABUF;
  #pragma unroll
  for (int p = 0; p < 2; ++p) gload16(gA[p] + aoff, nA + p * 8192 + wvoff);
  if (lane < 16) gload16(gAt + aoff, nA + 16384);   // rows 256..259
}

static __device__ __forceinline__ void domfma(
    iv4 (&Af)[4], iv4 (&Bf)[4], iv4 (&acc)[4][4]) {
  __builtin_amdgcn_s_setprio(1);
  #pragma unroll
  for (int n = 0; n < 4; ++n)
    #pragma unroll
    for (int m = 0; m < 4; ++m)
      acc[m][n] = __builtin_amdgcn_mfma_i32_16x16x64_i8(Af[m], Bf[n], acc[m][n], 0, 0, 0);
  __builtin_amdgcn_s_setprio(0);
}

static __device__ __forceinline__ void gates_(int W4) {}

// kk>=3 step: full pre-read of next step's fragments
template<int J, int W, int J3, int DADD, int DOA, int SET, int PRE, int PJ, int PDADD>
static __device__ __forceinline__ void stepN(
    int d0i, int bsl0, char* sA, char* sB,
    const char* const (&gA)[2], const char* gAt, const char* gB0,
    int lane, int wr, int wc, int lrow, int lg, int wvoff,
    iv4 (&Af0)[4], iv4 (&Bf0)[4], iv4 (&Af1)[4], iv4 (&Bf1)[4],
    iv4 (&acc)[4][4]) {
  {
    int dsl = (bsl0 + J + 3) & 3;
    gload16(gB0 + J3 * JSTRIDE + (d0i + DADD) * 64, sB + dsl * BSLOT + wvoff);
  }
  if constexpr (DOA) issueA(d0i, sA, gA, gAt, lane, wvoff);
  if constexpr (PRE) {
    int psl = (bsl0 + J + 1) & 3;
    const char* pA = sA + ((d0i + PDADD) & 1) * ABUF;
    const char* pB = sB + psl * BSLOT;
    iv4 (&Afn)[4] = sel<(SET ^ 1)>(Af0, Af1);
    iv4 (&Bfn)[4] = sel<(SET ^ 1)>(Bf0, Bf1);
    #pragma unroll
    for (int n = 0; n < 4; ++n) {
      int row = wc * 64 + n * 16 + lrow;
      Bfn[n] = *(const iv4*)(pB + row * 64 + ((lg ^ ((row >> 1) & 3)) << 4));
    }
    #pragma unroll
    for (int m = 0; m < 4; ++m) {
      int row = wr * 64 + m * 16 + lrow + PJ;
      Afn[m] = *(const iv4*)(pA + row * 64 + ((lg ^ ((row >> 1) & 3)) << 4));
    }
  }
  domfma(sel<SET>(Af0, Af1), sel<SET>(Bf0, Bf1), acc);
  __builtin_amdgcn_sched_barrier(0);
  waitv<W>();
  __builtin_amdgcn_sched_barrier(0);
  __builtin_amdgcn_s_barrier();
  __builtin_amdgcn_sched_barrier(0);
}

// kk==2 step: A read in-step (its pre-read window is unsafe), B pre-read
template<int J, int W, int J3, int DADD, int DOA, int SET, int PRE>
static __device__ __forceinline__ void step2(
    int d0i, int bsl0, char* sA, char* sB,
    const char* const (&gA)[2], const char* gAt, const char* gB0,
    int lane, int wr, int wc, int lrow, int lg, int wvoff,
    iv4 (&Bf0)[4], iv4 (&Bf1)[4], iv4 (&acc)[4][4]) {
  {
    int dsl = (bsl0 + J + 3) & 3;
    gload16(gB0 + J3 * JSTRIDE + (d0i + DADD) * 64, sB + dsl * BSLOT + wvoff);
  }
  if constexpr (DOA) issueA(d0i, sA, gA, gAt, lane, wvoff);
  const char* pA = sA + (d0i & 1) * ABUF;
  iv4 Af[4];
  #pragma unroll
  for (int m = 0; m < 4; ++m) {
    int row = wr * 64 + m * 16 + lrow + J;
    Af[m] = *(const iv4*)(pA + row * 64 + ((lg ^ ((row >> 1) & 3)) << 4));
  }
  if constexpr (PRE) {
    int psl = (bsl0 + J + 1) & 3;
    const char* pB = sB + psl * BSLOT;
    iv4 (&Bfn)[4] = sel<(SET ^ 1)>(Bf0, Bf1);
    #pragma unroll
    for (int n = 0; n < 4; ++n) {
      int row = wc * 64 + n * 16 + lrow;
      Bfn[n] = *(const iv4*)(pB + row * 64 + ((lg ^ ((row >> 1) & 3)) << 4));
    }
  }
  domfma(Af, sel<SET>(Bf0, Bf1), acc);
  __builtin_amdgcn_sched_barrier(0);
  waitv<W>();
  __builtin_amdgcn_sched_barrier(0);
  __builtin_amdgcn_s_barrier();
  __builtin_amdgcn_sched_barrier(0);
}

#define SN bsl0, sA, sB, gA, gAt, gB0, lane, wr, wc, lrow, lg, wvoff, Af0, Bf0, Af1, Bf1, acc
#define S2 bsl0, sA, sB, gA, gAt, gB0, lane, wr, wc, lrow, lg, wvoff, Bf0, Bf1, acc

template<int KK>
static __device__ __forceinline__ void conv_loop(
    char* sA, char* sB, const char* const (&gA)[2], const char* gAt,
    const char* gB0,
    int lane, int wr, int wc, int lrow, int lg, int wvoff, iv4 (&acc)[4][4]) {
  iv4 Af0[4], Bf0[4], Af1[4], Bf1[4];
  // prologue: A(0) + B slots 0,1,2 (steps 0,1,2); drain; pre-read step 0.
  #pragma unroll
  for (int p = 0; p < 2; ++p) gload16(gA[p], sA + p * 8192 + wvoff);
  if (lane < 16) gload16(gAt, sA + 16384);
  gload16(gB0, sB + wvoff);
  gload16(gB0 + JSTRIDE, sB + BSLOT + wvoff);
  constexpr int OFF2 = (KK >= 3) ? 2 * JSTRIDE : 64;   // step2 = (0,2) or (1,0)
  gload16(gB0 + OFF2, sB + 2 * BSLOT + wvoff);
  __builtin_amdgcn_sched_barrier(0);
  waitv<0>();
  __builtin_amdgcn_sched_barrier(0);
  __builtin_amdgcn_s_barrier();
  __builtin_amdgcn_sched_barrier(0);
  {
    #pragma unroll
    for (int n = 0; n < 4; ++n) {
      int row = wc * 64 + n * 16 + lrow;
      Bf0[n] = *(const iv4*)(sB + row * 64 + ((lg ^ ((row >> 1) & 3)) << 4));
    }
    if constexpr (KK >= 3) {
      #pragma unroll
      for (int m = 0; m < 4; ++m) {
        int row = wr * 64 + m * 16 + lrow;
        Af0[m] = *(const iv4*)(sA + row * 64 + ((lg ^ ((row >> 1) & 3)) << 4));
      }
    }
  }
  int bsl0 = 0;
  if constexpr (KK == 5) {
    for (int dd = 0; dd < 10; dd += 2) {
      stepN<0,4,3,0,1, 0,1,1,0>(dd, SN);
      stepN<1,4,4,0,0, 1,1,2,0>(dd, SN);
      stepN<2,1,0,1,0, 0,1,3,0>(dd, SN);
      stepN<3,1,1,1,0, 1,1,4,0>(dd, SN);
      stepN<4,1,2,1,0, 0,1,0,1>(dd, SN);
      bsl0 = (bsl0 + 5) & 3;
      stepN<0,4,3,0,1, 1,1,1,0>(dd + 1, SN);
      stepN<1,4,4,0,0, 0,1,2,0>(dd + 1, SN);
      stepN<2,1,0,1,0, 1,1,3,0>(dd + 1, SN);
      stepN<3,1,1,1,0, 0,1,4,0>(dd + 1, SN);
      stepN<4,1,2,1,0, 1,1,0,1>(dd + 1, SN);
      bsl0 = (bsl0 + 5) & 3;
    }
    stepN<0,4,3,0,1, 0,1,1,0>(10, SN);   // d0=10 (issues A(11))
    stepN<1,4,4,0,0, 1,1,2,0>(10, SN);
    stepN<2,1,0,1,0, 0,1,3,0>(10, SN);
    stepN<3,1,1,1,0, 1,1,4,0>(10, SN);
    stepN<4,1,2,1,0, 0,1,0,1>(10, SN);
    bsl0 = (bsl0 + 5) & 3;
    stepN<0,1,3,0,0, 1,1,1,0>(11, SN);   // tail d0: W=1, no A issue
    stepN<1,1,4,0,0, 0,1,2,0>(11, SN);
    stepN<2,1,0,1,0, 1,1,3,0>(11, SN);
    stepN<3,1,1,1,0, 0,1,4,0>(11, SN);
    stepN<4,1,2,1,0, 1,0,0,0>(11, SN);   // final: no pre-read
  } else if constexpr (KK == 4) {
    for (int dd = 0; dd < 11; ++dd) {
      stepN<0,4,3,0,1, 0,1,1,0>(dd, SN);
      stepN<1,4,0,1,0, 1,1,2,0>(dd, SN);
      stepN<2,1,1,1,0, 0,1,3,0>(dd, SN);
      stepN<3,1,2,1,0, 1,1,0,1>(dd, SN);
    }
    stepN<0,1,3,0,0, 0,1,1,0>(11, SN);
    stepN<1,1,0,1,0, 1,1,2,0>(11, SN);
    stepN<2,1,1,1,0, 0,1,3,0>(11, SN);
    stepN<3,1,2,1,0, 1,0,0,0>(11, SN);
  } else if constexpr (KK == 3) {
    for (int dd = 0; dd < 10; dd += 2) {
      stepN<0,4,0,1,1, 0,1,1,0>(dd, SN);
      stepN<1,1,1,1,0, 1,1,2,0>(dd, SN);
      stepN<2,1,2,1,0, 0,1,0,1>(dd, SN);
      bsl0 = (bsl0 + 3) & 3;
      stepN<0,4,0,1,1, 1,1,1,0>(dd + 1, SN);
      stepN<1,1,1,1,0, 0,1,2,0>(dd + 1, SN);
      stepN<2,1,2,1,0, 1,1,0,1>(dd + 1, SN);
      bsl0 = (bsl0 + 3) & 3;
    }
    stepN<0,4,0,1,1, 0,1,1,0>(10, SN);
    stepN<1,1,1,1,0, 1,1,2,0>(10, SN);
    stepN<2,1,2,1,0, 0,1,0,1>(10, SN);
    bsl0 = (bsl0 + 3) & 3;
    stepN<0,1,0,1,0, 1,1,1,0>(11, SN);
    stepN<1,1,1,1,0, 0,1,2,0>(11, SN);
    stepN<2,1,2,1,0, 1,0,0,0>(11, SN);
  } else {  // KK == 2
    for (int dd = 0; dd < 11; ++dd) {
      step2<0,4,1,1,1, 0,1>(dd, S2);
      step2<1,1,0,2,0, 1,1>(dd, S2);
      bsl0 = (bsl0 + 2) & 3;
    }
    step2<0,1,1,1,0, 0,1>(11, S2);
    step2<1,1,0,2,0, 1,0>(11, S2);
  }
  waitv<0>();                       // no DMA may outlive this block's LDS
}

__global__ __launch_bounds__(512, 2) void conv_kernel(
    const signed char* __restrict__ hcq, const signed char* __restrict__ wq,
    const float* __restrict__ b2, const float* __restrict__ b3,
    const float* __restrict__ b4, const float* __restrict__ b5,
    const float* __restrict__ fscale,
    const int* __restrict__ plan, const int* __restrict__ rowmap,
    int* __restrict__ feats) {
  __shared__ char smem[2 * ABUF + 4 * BSLOT];   // 66048 B
  char* sA = smem;
  char* sB = smem + 2 * ABUF;
  int idx = blockIdx.x;
  // XCD-aware decode: tile ≡ xcd (mod 8) so all 8 subs of a tile share an XCD
  int xcd = idx & 7, s2 = idx >> 3;
  int sub = s2 & 7, tile = xcd + ((s2 >> 3) << 3);
  if (tile >= plan[0]) return;
  int br = 3 - (sub >> 1), ff = sub & 1, kk = br + 2;
  int mBase = 256 * ((br * (br + 3)) >> 1) + ff * 128;
  const float* bias = (br == 0) ? b2 : (br == 1) ? b3 : (br == 2) ? b4 : b5;
  int tid = threadIdx.x, lane = tid & 63, wv = tid >> 6;
  int wr = wv >> 1, wc = wv & 1;     // wave tile: 64t x 64f
  int lrow = lane & 15, lg = lane >> 4;
  int wvoff = wv * 1024;
  int P0 = tile << 8;

  // per-lane pre-swizzled global sources (d0-invariant)
  const char* gA[2];
  #pragma unroll
  for (int p = 0; p < 2; ++p) {
    int c = p * 512 + tid;
    int row = c >> 2, sgp = c & 3;
    int rm = rowmap[P0 + row];
    int bb_ = rm >> 20, t = rm & 1023;
    int seg = sgp ^ ((row >> 1) & 3);
    gA[p] = (const char*)(hcq + ((size_t)(bb_ * SPn + t)) * Dn + seg * 16);
  }
  const char* gAt;
  {
    int l = lane & 15;               // rows 256..259 (lanes<16, all waves dup)
    int row = 256 + (l >> 2), sgp = l & 3;
    int rm = rowmap[P0 + row];
    int bb_ = rm >> 20, t = rm & 1023;
    int seg = sgp ^ ((row >> 1) & 3);
    gAt = (const char*)(hcq + ((size_t)(bb_ * SPn + t)) * Dn + seg * 16);
  }
  const char* gB0;
  {
    int row = tid >> 2, sgp = tid & 3;   // 512 chunks = 128 rows x 4 segs
    int seg = sgp ^ ((row >> 1) & 3);
    gB0 = (const char*)(wq + ((size_t)(mBase + row)) * Dn + seg * 16);
  }

  iv4 acc[4][4];
  #pragma unroll
  for (int m = 0; m < 4; ++m)
    #pragma unroll
    for (int n = 0; n < 4; ++n) acc[m][n] = (iv4)0;

  switch (br) {
    case 3: conv_loop<5>(sA, sB, gA, gAt, gB0, lane, wr, wc, lrow, lg, wvoff, acc); break;
    case 2: conv_loop<4>(sA, sB, gA, gAt, gB0, lane, wr, wc, lrow, lg, wvoff, acc); break;
    case 1: conv_loop<3>(sA, sB, gA, gAt, gB0, lane, wr, wc, lrow, lg, wvoff, acc); break;
    default: conv_loop<2>(sA, sB, gA, gAt, gB0, lane, wr, wc, lrow, lg, wvoff, acc); break;
  }

  // epilogue: dequant (s_a * s_f) + bias + mask + relu + pool + atomic
  int rmv[4];
  #pragma unroll
  for (int m = 0; m < 4; ++m) rmv[m] = rowmap[P0 + wr * 64 + m * 16];
  #pragma unroll
  for (int n = 0; n < 4; ++n) {
    int fg = ff * 128 + wc * 64 + n * 16 + lrow;
    float bv = bias[fg];
    float sfc = fscale[br * 256 + fg] * SAQ;
    #pragma unroll
    for (int m = 0; m < 4; ++m) {
      int bb_ = rmv[m] >> 20;
      int Lb = (rmv[m] >> 10) & 1023;
      int t0 = (rmv[m] & 1023) + lg * 4;
      int vlim = Lb - kk + 1;
      float pmax = 0.f;
      #pragma unroll
      for (int i = 0; i < 4; ++i) {
        float v = (float)acc[m][n][i] * sfc + bv;
        pmax = fmaxf(pmax, (t0 + i < vlim) ? fmaxf(v, 0.f) : 0.f);
      }
      pmax = fmaxf(pmax, __shfl_xor(pmax, 16));
      pmax = fmaxf(pmax, __shfl_xor(pmax, 32));
      if (lane < 16 && pmax > 0.f)
        atomicMax(feats + bb_ * 1024 + br * 256 + fg, __float_as_int(pmax));
    }
  }
}

// ---------------------------------------------------------------------------
// 4) FC + sigmoid
// ---------------------------------------------------------------------------
__global__ __launch_bounds__(64) void fc_kernel(
    const int* __restrict__ feats, const float* __restrict__ fcw,
    const float* __restrict__ fcb, float* __restrict__ out) {
  int b = blockIdx.x, lane = threadIdx.x;
  float acc = 0.f;
  for (int i = lane; i < 1024; i += 64)
    acc += __int_as_float(feats[b * 1024 + i]) * fcw[i];
  #pragma unroll
  for (int off = 32; off; off >>= 1) acc += __shfl_xor(acc, off);
  if (lane == 0) out[b] = 1.f / (1.f + expf(-(acc + fcb[0])));
}

extern "C" void kernel_launch(void* const* d_in, const int* in_sizes, int n_in,
                              void* d_out, int out_size, void* d_ws, size_t ws_size,
                              hipStream_t stream) {
  const int*   x   = (const int*)d_in[0];
  const float* h   = (const float*)d_in[1];
  const float* w2  = (const float*)d_in[2];
  const float* b2  = (const float*)d_in[3];
  const float* w3  = (const float*)d_in[4];
  const float* b3  = (const float*)d_in[5];
  const float* w4  = (const float*)d_in[6];
  const float* b4  = (const float*)d_in[7];
  const float* w5  = (const float*)d_in[8];
  const float* b5  = (const float*)d_in[9];
  const float* fcw = (const float*)d_in[10];
  const float* fcb = (const float*)d_in[11];
  float* out = (float*)d_out;
  char* ws = (char*)d_ws;
  signed char* hcq = (signed char*)ws;                    // 64*520*768   = 25,559,040
  signed char* wq  = (signed char*)(ws + 25559040);       // 3584*768     =  2,752,512
  float* fscale = (float*)(ws + 28311552);                // 1024*4
  int* feats  = (int*)(ws + 28315648);                    // 64*1024*4    =    262,144
  int* plan   = (int*)(ws + 28577792);                    // 4 ints
  int* rowmap = (int*)(ws + 28577808);                    // (32768+264)*4

  plan_kernel<<<1, 256, 0, stream>>>(x, plan, rowmap, feats);
  stage_kernel<<<1536, 256, 0, stream>>>(x, h, w2, w3, w4, w5, hcq, wq, fscale);
  conv_kernel<<<1024, 512, 0, stream>>>(hcq, wq, b2, b3, b4, b5, fscale, plan, rowmap, feats);
  fc_kernel<<<64, 64, 0, stream>>>(feats, fcw, fcb, out);
}